// Round 9
// baseline (70.371 us; speedup 1.0000x reference)
//
#include <hip/hip_runtime.h>

#define SPATIAL_SCALE 0.0625f
#define PH 7
#define PW 7
#define SR 2
#define C_TOTAL 1024
#define NXCD 8
#define NPOS 49
#define CG 128            // channels per slab (one per XCD)
#define NG 8              // slabs
#define HH 50
#define WW 50
#define ROWSTRIDE (WW * CG)          // 6400 floats
#define SLABSTRIDE (HH * WW * CG)    // 320000 floats
#define T_BYTES (2ULL * NG * HH * WW * CG * 4ULL)   // 20,480,000

typedef float f2v __attribute__((ext_vector_type(2), aligned(8)));
typedef float f4v __attribute__((ext_vector_type(4), aligned(8)));
typedef float f4a __attribute__((ext_vector_type(4), aligned(16)));

// ---------------- Kernel 1: NCHW -> [b][g][y][x][cg] channels-last ----------
__global__ __launch_bounds__(256) void transpose_kernel(
    const float* __restrict__ in, float* __restrict__ T)
{
    __shared__ float lds[CG][33];    // +1 pad: conflict-free both phases
    int bid = blockIdx.x;            // ((b*NG+g)*50 + y)*2 + xt
    int xt = bid & 1;
    int r  = bid >> 1;
    int y  = r % HH;
    int r2 = r / HH;
    int g  = r2 & 7;
    int b  = r2 >> 3;
    int tid = threadIdx.x;

    #pragma unroll
    for (int i = 0; i < 16; ++i) {           // 4096 elems = 128c x 32x
        int idx = i * 256 + tid;
        int cl = idx >> 5;                   // 0..127
        int xl = idx & 31;
        int x  = xt * 32 + xl;
        if (x < WW)
            lds[cl][xl] = in[(unsigned)(b * C_TOTAL + g * CG + cl) * (HH * WW)
                             + (unsigned)(y * WW + x)];
    }
    __syncthreads();
    #pragma unroll
    for (int i = 0; i < 16; ++i) {
        int idx = i * 256 + tid;
        int xl = idx >> 7;                   // 0..31
        int cg = idx & 127;
        int x  = xt * 32 + xl;
        if (x < WW)
            T[(unsigned)((b * NG + g) * (HH * WW) + y * WW + x) * CG + cg]
                = lds[cg][xl];
    }
}

// ---------------- Kernel 2: channels-last ROI align (coalesced taps) --------
// Block = (roi n, slab g). blockIdx&7 = g -> XCD-pinned 2.56MB slab.
// Wave wid handles ph = wid, wid+4; lane = 2 channels (cg = lane*2).
// Per bin: (2+q)x(2+dx) taps, each tap = one coalesced 512B wave-load.
__global__ __launch_bounds__(256) void roi_cl_kernel(
    const float* __restrict__ T,
    const float* __restrict__ rois,
    float* __restrict__ out, int N)
{
    __shared__ __align__(16) float so[CG * NPOS];   // 25088 B

    int g = blockIdx.x & (NXCD - 1);
    int n = blockIdx.x >> 3;
    int wid  = threadIdx.x >> 6;
    int lane = threadIdx.x & 63;
    int cg = lane * 2;

    const float* roi = rois + n * 5;
    int   b  = (int)roi[0];
    float x1 = roi[1] * SPATIAL_SCALE;
    float y1 = roi[2] * SPATIAL_SCALE;
    float x2 = roi[3] * SPATIAL_SCALE;
    float y2 = roi[4] * SPATIAL_SCALE;
    float roi_w = fmaxf(x2 - x1, 1.0f);
    float roi_h = fmaxf(y2 - y1, 1.0f);
    float bin_w = roi_w * (1.0f / PW);
    float bin_h = roi_h * (1.0f / PH);

    const float* base = T + (unsigned)(b * NG + g) * SLABSTRIDE + cg;

    for (int ph = wid; ph < PH; ph += 4) {   // uniform per wave
        // ---- y: 2 samples -> rows yl0, yl0+1 (+ yl0+2 iff q) ----
        float yc0 = y1 + ((float)(ph * SR + 0) + 0.5f) * bin_h * (1.0f / SR);
        float yc1 = y1 + ((float)(ph * SR + 1) + 0.5f) * bin_h * (1.0f / SR);
        float vy0 = (yc0 >= -1.0f && yc0 <= (float)HH) ? 1.0f : 0.0f;
        float vy1 = (yc1 >= -1.0f && yc1 <= (float)HH) ? 1.0f : 0.0f;
        float ycl0 = fminf(fmaxf(yc0, 0.0f), (float)(HH - 1));
        float ycl1 = fminf(fmaxf(yc1, 0.0f), (float)(HH - 1));
        int yl0 = min(max((int)floorf(ycl0), 0), HH - 2);
        int yl1 = min(max((int)floorf(ycl1), 0), HH - 2);
        float ly0 = ycl0 - (float)yl0, hy0 = 1.0f - ly0;
        float ly1 = ycl1 - (float)yl1, hy1 = 1.0f - ly1;
        float wy0 = 0.25f * vy0 * hy0;
        float wy1 = 0.25f * vy0 * ly0;
        float wy2 = 0.25f * vy1 * hy1;
        float wy3 = 0.25f * vy1 * ly1;
        int q = yl1 - yl0;               // 0 or 1
        float wr0 = wy0 + ((q == 0) ? wy2 : 0.0f);
        float wr1 = wy1 + ((q == 0) ? wy3 : wy2);
        float wr2 = (q == 0) ? 0.0f : wy3;   // row yl0+2 (in-bounds when q==1)

        const float* rowp = base + (unsigned)(yl0 * WW) * CG;

        #pragma unroll
        for (int pw = 0; pw < PW; ++pw) {
            // ---- x: 2 samples -> cols xl0, xl0+1 (+ xl0+2 iff dx) ----
            float xc0 = x1 + ((float)(pw * SR + 0) + 0.5f) * bin_w * (1.0f / SR);
            float xc1 = x1 + ((float)(pw * SR + 1) + 0.5f) * bin_w * (1.0f / SR);
            float vx0 = (xc0 >= -1.0f && xc0 <= (float)WW) ? 1.0f : 0.0f;
            float vx1 = (xc1 >= -1.0f && xc1 <= (float)WW) ? 1.0f : 0.0f;
            float xcl0 = fminf(fmaxf(xc0, 0.0f), (float)(WW - 1));
            float xcl1 = fminf(fmaxf(xc1, 0.0f), (float)(WW - 1));
            int xl0 = min(max((int)floorf(xcl0), 0), WW - 2);
            int xl1 = min(max((int)floorf(xcl1), 0), WW - 2);
            float lx0 = xcl0 - (float)xl0, hx0 = 1.0f - lx0;
            float lx1 = xcl1 - (float)xl1, hx1 = 1.0f - lx1;
            int dx = xl1 - xl0;          // 0 or 1
            float u0 = vx0 * hx0 + ((dx == 0) ? vx1 * hx1 : 0.0f);
            float u1 = vx0 * lx0 + ((dx == 0) ? vx1 * lx1 : vx1 * hx1);
            float u2 = (dx == 0) ? 0.0f : vx1 * lx1;

            const float* p = rowp + (unsigned)(xl0) * CG;

            f2v t00 = *(const f2v*)(p);
            f2v t10 = *(const f2v*)(p + ROWSTRIDE);
            f2v t01 = *(const f2v*)(p + CG);
            f2v t11 = *(const f2v*)(p + ROWSTRIDE + CG);
            f2v cs0 = wr0 * t00 + wr1 * t10;
            f2v cs1 = wr0 * t01 + wr1 * t11;
            if (q) {                     // uniform branch (one ROI per block)
                cs0 += wr2 * *(const f2v*)(p + 2 * ROWSTRIDE);
                cs1 += wr2 * *(const f2v*)(p + 2 * ROWSTRIDE + CG);
            }
            f2v acc = u0 * cs0 + u1 * cs1;
            if (dx) {
                f2v t02 = *(const f2v*)(p + 2 * CG);
                f2v t12 = *(const f2v*)(p + ROWSTRIDE + 2 * CG);
                f2v cs2 = wr0 * t02 + wr1 * t12;
                if (q) cs2 += wr2 * *(const f2v*)(p + 2 * ROWSTRIDE + 2 * CG);
                acc += u2 * cs2;
            }
            int s = ph * PW + pw;
            so[cg * NPOS + s]       = acc[0];
            so[(cg + 1) * NPOS + s] = acc[1];
        }
    }

    __syncthreads();

    // ---- coalesced b128 writeback of the block's contiguous 25088B ----
    unsigned obase = (unsigned)(n * C_TOTAL + g * CG) * NPOS;
    f4a* dst = (f4a*)(out + obase);
    const f4a* src = (const f4a*)so;
    int tid = threadIdx.x;
    // 128*49/4 = 1568 f4 elements = 6*256 + 32
    #pragma unroll
    for (int k = 0; k < 6; ++k)
        dst[k * 256 + tid] = src[k * 256 + tid];
    if (tid < 32) dst[1536 + tid] = src[1536 + tid];
}

// ---------------- Fallback (R7 kernel) if ws_size too small -----------------
__global__ __launch_bounds__(256) void roi_align_fallback(
    const float* __restrict__ data, const float* __restrict__ rois,
    float* __restrict__ out, int H, int W, int N)
{
    __shared__ __align__(16) float so[64 * NPOS];
    int i   = blockIdx.x;
    int xcd = i & (NXCD - 1);
    int j   = i >> 3;
    int scl = (j >= N) ? 1 : 0;
    int n   = j - scl * N;
    int superchunk = xcd * 2 + scl;
    int t = threadIdx.x;
    bool active = (t < 5 * NPOS);
    int tt = active ? t : 0;
    int s  = tt % NPOS;
    int g  = tt / NPOS;
    int cbase = g * 13;
    int cnt = (g < 4) ? 13 : 12;
    int pw = s % PW;
    int ph = s / PW;
    if (active) {
        const float* roi = rois + n * 5;
        int   b  = (int)roi[0];
        float x1 = roi[1] * SPATIAL_SCALE, y1 = roi[2] * SPATIAL_SCALE;
        float x2 = roi[3] * SPATIAL_SCALE, y2 = roi[4] * SPATIAL_SCALE;
        float roi_w = fmaxf(x2 - x1, 1.0f), roi_h = fmaxf(y2 - y1, 1.0f);
        float bin_w = roi_w * (1.0f / PW), bin_h = roi_h * (1.0f / PH);
        float xc0 = x1 + ((float)(pw * SR + 0) + 0.5f) * bin_w * (1.0f / SR);
        float xc1 = x1 + ((float)(pw * SR + 1) + 0.5f) * bin_w * (1.0f / SR);
        float vx0 = (xc0 >= -1.0f && xc0 <= (float)W) ? 1.0f : 0.0f;
        float vx1 = (xc1 >= -1.0f && xc1 <= (float)W) ? 1.0f : 0.0f;
        float xcl0 = fminf(fmaxf(xc0, 0.0f), (float)(W - 1));
        float xcl1 = fminf(fmaxf(xc1, 0.0f), (float)(W - 1));
        int xl0 = min(max((int)floorf(xcl0), 0), W - 2);
        int xl1 = min(max((int)floorf(xcl1), 0), W - 2);
        float lx0 = xcl0 - (float)xl0, hx0 = 1.0f - lx0;
        float lx1 = xcl1 - (float)xl1, hx1 = 1.0f - lx1;
        int xb = min(xl0 & ~1, W - 4);
        int p0 = xl0 - xb, p1 = xl1 - xb;
        float w4[4];
        #pragma unroll
        for (int k = 0; k < 4; ++k) {
            float a = (p0 == k) ? hx0 : ((p0 + 1 == k) ? lx0 : 0.0f);
            float c = (p1 == k) ? hx1 : ((p1 + 1 == k) ? lx1 : 0.0f);
            w4[k] = vx0 * a + vx1 * c;
        }
        float yc0 = y1 + ((float)(ph * SR + 0) + 0.5f) * bin_h * (1.0f / SR);
        float yc1 = y1 + ((float)(ph * SR + 1) + 0.5f) * bin_h * (1.0f / SR);
        float vy0 = (yc0 >= -1.0f && yc0 <= (float)H) ? 1.0f : 0.0f;
        float vy1 = (yc1 >= -1.0f && yc1 <= (float)H) ? 1.0f : 0.0f;
        float ycl0 = fminf(fmaxf(yc0, 0.0f), (float)(H - 1));
        float ycl1 = fminf(fmaxf(yc1, 0.0f), (float)(H - 1));
        int yl0 = min(max((int)floorf(ycl0), 0), H - 2);
        int yl1 = min(max((int)floorf(ycl1), 0), H - 2);
        float ly0 = ycl0 - (float)yl0, hy0 = 1.0f - ly0;
        float ly1 = ycl1 - (float)yl1, hy1 = 1.0f - ly1;
        float wy0 = 0.25f * vy0 * hy0, wy1 = 0.25f * vy0 * ly0;
        float wy2 = 0.25f * vy1 * hy1, wy3 = 0.25f * vy1 * ly1;
        int q = yl1 - yl0;
        float wr0 = wy0 + ((q == 0) ? wy2 : 0.0f);
        float wr1 = wy1 + ((q == 0) ? wy3 : wy2);
        float wr2 = (q == 0) ? 0.0f : wy3;
        int row0 = yl0;
        int row2 = min(yl0 + 2, H - 1);
        float wv[3][4];
        #pragma unroll
        for (int k = 0; k < 4; ++k) {
            wv[0][k] = wr0 * w4[k]; wv[1][k] = wr1 * w4[k]; wv[2][k] = wr2 * w4[k];
        }
        int c0 = superchunk * 64 + cbase;
        const int HW = H * W;
        unsigned slab = (unsigned)(b * C_TOTAL + c0) * (unsigned)HW;
        unsigned o0 = slab + (unsigned)(row0 * W + xb);
        unsigned o1 = o0 + (unsigned)W;
        unsigned o2 = slab + (unsigned)(row2 * W + xb);
        int ldsbase = cbase * NPOS + s;
        f4v a0 = *(const f4v*)(data + o0);
        f4v a1 = *(const f4v*)(data + o1);
        f4v a2 = *(const f4v*)(data + o2);
        int jj = 0;
        for (; jj < cnt - 1; ++jj) {
            o0 += HW; o1 += HW; o2 += HW;
            f4v b0 = *(const f4v*)(data + o0);
            f4v b1 = *(const f4v*)(data + o1);
            f4v b2 = *(const f4v*)(data + o2);
            float acc = wv[0][0]*a0.x + wv[0][1]*a0.y + wv[0][2]*a0.z + wv[0][3]*a0.w
                      + wv[1][0]*a1.x + wv[1][1]*a1.y + wv[1][2]*a1.z + wv[1][3]*a1.w
                      + wv[2][0]*a2.x + wv[2][1]*a2.y + wv[2][2]*a2.z + wv[2][3]*a2.w;
            so[ldsbase + jj * NPOS] = acc;
            a0 = b0; a1 = b1; a2 = b2;
        }
        float acc = wv[0][0]*a0.x + wv[0][1]*a0.y + wv[0][2]*a0.z + wv[0][3]*a0.w
                  + wv[1][0]*a1.x + wv[1][1]*a1.y + wv[1][2]*a1.z + wv[1][3]*a1.w
                  + wv[2][0]*a2.x + wv[2][1]*a2.y + wv[2][2]*a2.z + wv[2][3]*a2.w;
        so[ldsbase + jj * NPOS] = acc;
    }
    __syncthreads();
    unsigned base = (unsigned)(n * C_TOTAL + superchunk * 64) * NPOS;
    f4a* dst = (f4a*)(out + base);
    const f4a* src = (const f4a*)so;
    int tid = threadIdx.x;
    dst[tid] = src[tid];
    dst[256 + tid] = src[256 + tid];
    dst[512 + tid] = src[512 + tid];
    if (tid < 16) dst[768 + tid] = src[768 + tid];
}

extern "C" void kernel_launch(void* const* d_in, const int* in_sizes, int n_in,
                              void* d_out, int out_size, void* d_ws, size_t ws_size,
                              hipStream_t stream) {
    const float* data = (const float*)d_in[0];
    const float* rois = (const float*)d_in[1];
    float* out = (float*)d_out;
    const int N = in_sizes[1] / 5;

    if (ws_size >= T_BYTES) {
        float* T = (float*)d_ws;
        transpose_kernel<<<2 * NG * HH * 2, 256, 0, stream>>>(data, T);
        roi_cl_kernel<<<N * NXCD, 256, 0, stream>>>(T, rois, out, N);
    } else {
        roi_align_fallback<<<N * 16, 256, 0, stream>>>(data, rois, out, 50, 50, N);
    }
}

// Round 10
// 65.595 us; speedup vs baseline: 1.0728x; 1.0728x over previous
//
#include <hip/hip_runtime.h>
#include <hip/hip_bf16.h>

#define SPATIAL_SCALE 0.0625f
#define PH 7
#define PW 7
#define SR 2
#define C_TOTAL 1024
#define NXCD 8
#define NPOS 49
#define CG 128
#define HH 50
#define WW 50
#define TB_BYTES (2ULL * NXCD * HH * WW * CG * 2ULL)   // 10,240,000 B (bf16)

typedef unsigned short us8v __attribute__((ext_vector_type(8), aligned(16)));
typedef float f4v __attribute__((ext_vector_type(4), aligned(8)));
typedef float f4a __attribute__((ext_vector_type(4), aligned(16)));

__device__ __forceinline__ float bf2f(unsigned short u) {
    union { unsigned int i; float f; } c; c.i = ((unsigned int)u) << 16; return c.f;
}

// ---- Kernel 1: NCHW fp32 -> [b][g][y][x][c] bf16 channels-last -------------
// bid&7 = g so each slab is written by (and L2-resident on) its own XCD.
__global__ __launch_bounds__(256) void transpose_bf16_kernel(
    const float* __restrict__ in, __hip_bfloat16* __restrict__ Tb)
{
    __shared__ float lds[CG][WW + 1];
    int bid = blockIdx.x;            // (b*50 + y)*8 + g
    int g = bid & 7;
    int r = bid >> 3;
    int y = r % HH;
    int b = r / HH;
    int tid = threadIdx.x;

    const float* src = in + (size_t)(b * C_TOTAL + g * CG) * (HH * WW) + y * WW;
    #pragma unroll
    for (int it = 0; it < 25; ++it) {        // 6400 = 128c x 50x
        int idx = it * 256 + tid;
        int c = idx / WW;
        int x = idx - c * WW;
        lds[c][x] = src[c * (HH * WW) + x];
    }
    __syncthreads();
    __hip_bfloat16* dst = Tb + (size_t)((b * NXCD + g) * (HH * WW) + y * WW) * CG;
    #pragma unroll
    for (int it = 0; it < 25; ++it) {
        int idx = it * 256 + tid;
        int x = idx >> 7;                    // 0..49
        int c = idx & 127;
        dst[x * CG + c] = __float2bfloat16(lds[c][x]);
    }
}

// ---- Kernel 2: bf16 channels-last ROI align ---------------------------------
// Block = (roi n, slab g); blockIdx&7 = g -> XCD-pinned 1.28MB bf16 slab.
// Lane = (col = lane>>4, ch8 = (lane&15)*8): ONE 1KB wave-load covers the
// whole 4-col x-window x 128 ch for a row. 3 branchless row loads per bin.
// Bins split across waves (m = wid + 4k). x-combine in-register via u[col]
// then shfl_xor 16/32 reduce; lanes<16 stage to LDS; coalesced b128 writeback.
struct BinT {
    unsigned o0, o1, o2;          // bf16-element offsets into slab (per-lane)
    float wr0, wr1, wr2, uc;
    int s;
};

__global__ __launch_bounds__(256) void roi_bf16_kernel(
    const __hip_bfloat16* __restrict__ Tb,
    const float* __restrict__ rois,
    float* __restrict__ out, int N)
{
    __shared__ __align__(16) float so[CG * NPOS];   // 25088 B

    int g = blockIdx.x & (NXCD - 1);
    int n = blockIdx.x >> 3;
    int wid  = threadIdx.x >> 6;
    int lane = threadIdx.x & 63;
    int col  = lane >> 4;
    int c8   = (lane & 15) * 8;
    unsigned laneoff = (unsigned)lane * 8;   // = col*128 + (lane&15)*8

    const float* roi = rois + n * 5;
    int   b  = (int)roi[0];
    float x1 = roi[1] * SPATIAL_SCALE;
    float y1 = roi[2] * SPATIAL_SCALE;
    float x2 = roi[3] * SPATIAL_SCALE;
    float y2 = roi[4] * SPATIAL_SCALE;
    float roi_w = fmaxf(x2 - x1, 1.0f);
    float roi_h = fmaxf(y2 - y1, 1.0f);
    float bin_w = roi_w * (1.0f / PW);
    float bin_h = roi_h * (1.0f / PH);
    float hbw = 0.5f * bin_w, hbh = 0.5f * bin_h;
    float xq = x1 + 0.5f * hbw;      // xc0 = pw*bin_w + xq
    float yq = y1 + 0.5f * hbh;      // yc0 = ph*bin_h + yq

    const __hip_bfloat16* slab = Tb + (size_t)((b * NXCD + g) * (HH * WW)) * CG;

    auto make_bin = [&](int m) -> BinT {
        BinT bn;
        int ph = m / 7;
        int pw = m - ph * 7;
        bn.s = m;
        // ---- y: 2 samples -> 3-row window, weight-0 clamp for row2 ----
        float yc0 = fmaf((float)ph, bin_h, yq);
        float yc1 = yc0 + hbh;
        float vy0 = (yc0 >= -1.0f && yc0 <= (float)HH) ? 1.0f : 0.0f;
        float vy1 = (yc1 >= -1.0f && yc1 <= (float)HH) ? 1.0f : 0.0f;
        float ycl0 = fminf(fmaxf(yc0, 0.0f), (float)(HH - 1));
        float ycl1 = fminf(fmaxf(yc1, 0.0f), (float)(HH - 1));
        int yl0 = min(max((int)floorf(ycl0), 0), HH - 2);
        int yl1 = min(max((int)floorf(ycl1), 0), HH - 2);
        float ly0 = ycl0 - (float)yl0, hy0 = 1.0f - ly0;
        float ly1 = ycl1 - (float)yl1, hy1 = 1.0f - ly1;
        float wy0 = 0.25f * vy0 * hy0;
        float wy1 = 0.25f * vy0 * ly0;
        float wy2 = 0.25f * vy1 * hy1;
        float wy3 = 0.25f * vy1 * ly1;
        int q = yl1 - yl0;                   // 0 or 1
        bn.wr0 = wy0 + ((q == 0) ? wy2 : 0.0f);
        bn.wr1 = wy1 + ((q == 0) ? wy3 : wy2);
        bn.wr2 = (q == 0) ? 0.0f : wy3;
        int r2 = min(yl0 + 2, HH - 1);       // clamped; wr2==0 when clamped
        // ---- x: 2 samples; 4-col window base xw covers all taps ----
        float xc0 = fmaf((float)pw, bin_w, xq);
        float xc1 = xc0 + hbw;
        float vx0 = (xc0 >= -1.0f && xc0 <= (float)WW) ? 1.0f : 0.0f;
        float vx1 = (xc1 >= -1.0f && xc1 <= (float)WW) ? 1.0f : 0.0f;
        float xcl0 = fminf(fmaxf(xc0, 0.0f), (float)(WW - 1));
        float xcl1 = fminf(fmaxf(xc1, 0.0f), (float)(WW - 1));
        int xl0 = min(max((int)floorf(xcl0), 0), WW - 2);
        int xl1 = min(max((int)floorf(xcl1), 0), WW - 2);
        float lx0 = xcl0 - (float)xl0, hx0 = 1.0f - lx0;
        float lx1 = xcl1 - (float)xl1, hx1 = 1.0f - lx1;
        int xw = min(xl0, WW - 4);           // window cols xw..xw+3
        int p0 = xl0 - xw;                   // {0,1,2}
        int p1 = xl1 - xw;                   // p1+1 <= 3 (proven)
        float u0 = vx0 * ((p0 == 0) ? hx0 : 0.0f) + vx1 * ((p1 == 0) ? hx1 : 0.0f);
        float u1 = vx0 * ((p0 == 1) ? hx0 : ((p0 == 0) ? lx0 : 0.0f))
                 + vx1 * ((p1 == 1) ? hx1 : ((p1 == 0) ? lx1 : 0.0f));
        float u2 = vx0 * ((p0 == 2) ? hx0 : ((p0 == 1) ? lx0 : 0.0f))
                 + vx1 * ((p1 == 2) ? hx1 : ((p1 == 1) ? lx1 : 0.0f));
        float u3 = vx0 * ((p0 + 1 == 3) ? lx0 : 0.0f)
                 + vx1 * ((p1 + 1 == 3) ? lx1 : 0.0f);
        bn.uc = (col & 2) ? ((col & 1) ? u3 : u2) : ((col & 1) ? u1 : u0);
        unsigned rowbase = (unsigned)(yl0 * WW + xw) * CG + laneoff;
        bn.o0 = rowbase;
        bn.o1 = rowbase + (unsigned)(WW * CG);
        bn.o2 = (unsigned)(r2 * WW + xw) * CG + laneoff;
        return bn;
    };

    int nb = (wid == 0) ? 13 : 12;           // bins m = wid + 4k, m < 49

    auto consume = [&](const BinT& bn, us8v a0, us8v a1, us8v a2) {
        float r[8];
        #pragma unroll
        for (int j = 0; j < 8; ++j) {
            float v = bn.wr0 * bf2f(a0[j]);
            v = fmaf(bn.wr1, bf2f(a1[j]), v);
            v = fmaf(bn.wr2, bf2f(a2[j]), v);
            r[j] = v * bn.uc;
        }
        #pragma unroll
        for (int j = 0; j < 8; ++j) r[j] += __shfl_xor(r[j], 16);
        #pragma unroll
        for (int j = 0; j < 8; ++j) r[j] += __shfl_xor(r[j], 32);
        if (lane < 16) {
            #pragma unroll
            for (int j = 0; j < 8; ++j)
                so[(c8 + j) * NPOS + bn.s] = r[j];
        }
    };

    BinT cur = make_bin(wid);
    us8v a0 = *(const us8v*)(slab + cur.o0);
    us8v a1 = *(const us8v*)(slab + cur.o1);
    us8v a2 = *(const us8v*)(slab + cur.o2);
    for (int k = 1; k < nb; ++k) {
        BinT nxt = make_bin(wid + 4 * k);
        us8v b0 = *(const us8v*)(slab + nxt.o0);
        us8v b1 = *(const us8v*)(slab + nxt.o1);
        us8v b2 = *(const us8v*)(slab + nxt.o2);
        consume(cur, a0, a1, a2);
        cur = nxt; a0 = b0; a1 = b1; a2 = b2;
    }
    consume(cur, a0, a1, a2);

    __syncthreads();

    // ---- coalesced b128 writeback of the block's contiguous 25088B ----
    unsigned obase = (unsigned)(n * C_TOTAL + g * CG) * NPOS;
    f4a* dst = (f4a*)(out + obase);
    const f4a* src = (const f4a*)so;
    int tid = threadIdx.x;
    #pragma unroll
    for (int k = 0; k < 6; ++k)
        dst[k * 256 + tid] = src[k * 256 + tid];
    if (tid < 32) dst[1536 + tid] = src[1536 + tid];
}

// ---- Fallback (fp32 direct, ~R7) if workspace too small --------------------
__global__ __launch_bounds__(256) void roi_align_fallback(
    const float* __restrict__ data, const float* __restrict__ rois,
    float* __restrict__ out, int H, int W, int N)
{
    __shared__ __align__(16) float so[64 * NPOS];
    int i   = blockIdx.x;
    int xcd = i & (NXCD - 1);
    int j   = i >> 3;
    int scl = (j >= N) ? 1 : 0;
    int n   = j - scl * N;
    int superchunk = xcd * 2 + scl;
    int t = threadIdx.x;
    bool active = (t < 5 * NPOS);
    int tt = active ? t : 0;
    int s  = tt % NPOS;
    int g  = tt / NPOS;
    int cbase = g * 13;
    int cnt = (g < 4) ? 13 : 12;
    int pw = s % PW;
    int ph = s / PW;
    if (active) {
        const float* roi = rois + n * 5;
        int   b  = (int)roi[0];
        float x1 = roi[1] * SPATIAL_SCALE, y1 = roi[2] * SPATIAL_SCALE;
        float x2 = roi[3] * SPATIAL_SCALE, y2 = roi[4] * SPATIAL_SCALE;
        float roi_w = fmaxf(x2 - x1, 1.0f), roi_h = fmaxf(y2 - y1, 1.0f);
        float bin_w = roi_w * (1.0f / PW), bin_h = roi_h * (1.0f / PH);
        float xc0 = x1 + ((float)(pw * SR + 0) + 0.5f) * bin_w * (1.0f / SR);
        float xc1 = x1 + ((float)(pw * SR + 1) + 0.5f) * bin_w * (1.0f / SR);
        float vx0 = (xc0 >= -1.0f && xc0 <= (float)W) ? 1.0f : 0.0f;
        float vx1 = (xc1 >= -1.0f && xc1 <= (float)W) ? 1.0f : 0.0f;
        float xcl0 = fminf(fmaxf(xc0, 0.0f), (float)(W - 1));
        float xcl1 = fminf(fmaxf(xc1, 0.0f), (float)(W - 1));
        int xl0 = min(max((int)floorf(xcl0), 0), W - 2);
        int xl1 = min(max((int)floorf(xcl1), 0), W - 2);
        float lx0 = xcl0 - (float)xl0, hx0 = 1.0f - lx0;
        float lx1 = xcl1 - (float)xl1, hx1 = 1.0f - lx1;
        int xb = min(xl0 & ~1, W - 4);
        int p0 = xl0 - xb, p1 = xl1 - xb;
        float w4[4];
        #pragma unroll
        for (int k = 0; k < 4; ++k) {
            float a = (p0 == k) ? hx0 : ((p0 + 1 == k) ? lx0 : 0.0f);
            float c = (p1 == k) ? hx1 : ((p1 + 1 == k) ? lx1 : 0.0f);
            w4[k] = vx0 * a + vx1 * c;
        }
        float yc0 = y1 + ((float)(ph * SR + 0) + 0.5f) * bin_h * (1.0f / SR);
        float yc1 = y1 + ((float)(ph * SR + 1) + 0.5f) * bin_h * (1.0f / SR);
        float vy0 = (yc0 >= -1.0f && yc0 <= (float)H) ? 1.0f : 0.0f;
        float vy1 = (yc1 >= -1.0f && yc1 <= (float)H) ? 1.0f : 0.0f;
        float ycl0 = fminf(fmaxf(yc0, 0.0f), (float)(H - 1));
        float ycl1 = fminf(fmaxf(yc1, 0.0f), (float)(H - 1));
        int yl0 = min(max((int)floorf(ycl0), 0), H - 2);
        int yl1 = min(max((int)floorf(ycl1), 0), H - 2);
        float ly0 = ycl0 - (float)yl0, hy0 = 1.0f - ly0;
        float ly1 = ycl1 - (float)yl1, hy1 = 1.0f - ly1;
        float wy0 = 0.25f * vy0 * hy0, wy1 = 0.25f * vy0 * ly0;
        float wy2 = 0.25f * vy1 * hy1, wy3 = 0.25f * vy1 * ly1;
        int q = yl1 - yl0;
        float wr0 = wy0 + ((q == 0) ? wy2 : 0.0f);
        float wr1 = wy1 + ((q == 0) ? wy3 : wy2);
        float wr2 = (q == 0) ? 0.0f : wy3;
        int row0 = yl0;
        int row2 = min(yl0 + 2, H - 1);
        float wv[3][4];
        #pragma unroll
        for (int k = 0; k < 4; ++k) {
            wv[0][k] = wr0 * w4[k]; wv[1][k] = wr1 * w4[k]; wv[2][k] = wr2 * w4[k];
        }
        int c0 = superchunk * 64 + cbase;
        const int HW = H * W;
        unsigned slab = (unsigned)(b * C_TOTAL + c0) * (unsigned)HW;
        unsigned o0 = slab + (unsigned)(row0 * W + xb);
        unsigned o1 = o0 + (unsigned)W;
        unsigned o2 = slab + (unsigned)(row2 * W + xb);
        int ldsbase = cbase * NPOS + s;
        f4v a0 = *(const f4v*)(data + o0);
        f4v a1 = *(const f4v*)(data + o1);
        f4v a2 = *(const f4v*)(data + o2);
        int jj = 0;
        for (; jj < cnt - 1; ++jj) {
            o0 += HW; o1 += HW; o2 += HW;
            f4v b0 = *(const f4v*)(data + o0);
            f4v b1 = *(const f4v*)(data + o1);
            f4v b2 = *(const f4v*)(data + o2);
            float acc = wv[0][0]*a0.x + wv[0][1]*a0.y + wv[0][2]*a0.z + wv[0][3]*a0.w
                      + wv[1][0]*a1.x + wv[1][1]*a1.y + wv[1][2]*a1.z + wv[1][3]*a1.w
                      + wv[2][0]*a2.x + wv[2][1]*a2.y + wv[2][2]*a2.z + wv[2][3]*a2.w;
            so[ldsbase + jj * NPOS] = acc;
            a0 = b0; a1 = b1; a2 = b2;
        }
        float acc = wv[0][0]*a0.x + wv[0][1]*a0.y + wv[0][2]*a0.z + wv[0][3]*a0.w
                  + wv[1][0]*a1.x + wv[1][1]*a1.y + wv[1][2]*a1.z + wv[1][3]*a1.w
                  + wv[2][0]*a2.x + wv[2][1]*a2.y + wv[2][2]*a2.z + wv[2][3]*a2.w;
        so[ldsbase + jj * NPOS] = acc;
    }
    __syncthreads();
    unsigned base = (unsigned)(n * C_TOTAL + superchunk * 64) * NPOS;
    f4a* dst = (f4a*)(out + base);
    const f4a* src = (const f4a*)so;
    int tid = threadIdx.x;
    dst[tid] = src[tid];
    dst[256 + tid] = src[256 + tid];
    dst[512 + tid] = src[512 + tid];
    if (tid < 16) dst[768 + tid] = src[768 + tid];
}

extern "C" void kernel_launch(void* const* d_in, const int* in_sizes, int n_in,
                              void* d_out, int out_size, void* d_ws, size_t ws_size,
                              hipStream_t stream) {
    const float* data = (const float*)d_in[0];
    const float* rois = (const float*)d_in[1];
    float* out = (float*)d_out;
    const int N = in_sizes[1] / 5;

    if (ws_size >= TB_BYTES) {
        __hip_bfloat16* Tb = (__hip_bfloat16*)d_ws;
        transpose_bf16_kernel<<<2 * HH * NXCD, 256, 0, stream>>>(data, Tb);
        roi_bf16_kernel<<<N * NXCD, 256, 0, stream>>>(Tb, rois, out, N);
    } else {
        roi_align_fallback<<<N * 16, 256, 0, stream>>>(data, rois, out, HH, WW, N);
    }
}

// Round 11
// 65.184 us; speedup vs baseline: 1.0796x; 1.0063x over previous
//
#include <hip/hip_runtime.h>
#include <hip/hip_bf16.h>

#define SPATIAL_SCALE 0.0625f
#define PH 7
#define PW 7
#define C_TOTAL 1024
#define NXCD 8
#define NPOS 49
#define CG 128
#define HH 50
#define WW 50
#define TB_BYTES (2ULL * NXCD * HH * WW * CG * 2ULL)   // 10,240,000 B (bf16)

typedef unsigned int u4v __attribute__((ext_vector_type(4), aligned(16)));
typedef float f4v __attribute__((ext_vector_type(4), aligned(8)));
typedef float f4a __attribute__((ext_vector_type(4), aligned(16)));

// ---- Kernel 1: NCHW fp32 -> [b][g][y][x][c] bf16 channels-last -------------
__global__ __launch_bounds__(256) void transpose_bf16_kernel(
    const float* __restrict__ in, __hip_bfloat16* __restrict__ Tb)
{
    __shared__ float lds[CG][WW + 1];
    int bid = blockIdx.x;            // (b*50 + y)*8 + g
    int g = bid & 7;
    int r = bid >> 3;
    int y = r % HH;
    int b = r / HH;
    int tid = threadIdx.x;

    const float* src = in + (size_t)(b * C_TOTAL + g * CG) * (HH * WW) + y * WW;
    #pragma unroll
    for (int it = 0; it < 25; ++it) {        // 6400 = 128c x 50x
        int idx = it * 256 + tid;
        int c = idx / WW;
        int x = idx - c * WW;
        lds[c][x] = src[c * (HH * WW) + x];
    }
    __syncthreads();
    __hip_bfloat16* dst = Tb + (size_t)((b * NXCD + g) * (HH * WW) + y * WW) * CG;
    #pragma unroll
    for (int it = 0; it < 25; ++it) {
        int idx = it * 256 + tid;
        int x = idx >> 7;                    // 0..49
        int c = idx & 127;
        dst[x * CG + c] = __float2bfloat16(lds[c][x]);
    }
}

// ---- Kernel 2: bf16 channels-last ROI align, hoisted params ----------------
// Block = (roi n, slab g); blockIdx&7 = g -> XCD-pinned 1.28MB bf16 slab.
// Phase 1: lanes<49 compute per-bin params ONCE into LDS.
// Phase 2: wave wid handles bins m = wid+4k. Per bin: 3 coalesced 1KB loads
// (lane = col*16 + octet, us8v), wa_r = wr_r*u[col] fold, 24 extract + 24 fma,
// shfl_xor 16/32 col-reduce, swizzled conflict-free LDS store.
// Phase 3: coalesced b128 writeback (swizzle-aware, alignment preserved).
__global__ __launch_bounds__(256) void roi_bf16_kernel(
    const __hip_bfloat16* __restrict__ Tb,
    const float* __restrict__ rois,
    float* __restrict__ out, int N)
{
    __shared__ __align__(16) float so[6300];     // 128*49 + swizzle slack
    __shared__ float prm[NPOS * 12];

    int g = blockIdx.x & (NXCD - 1);
    int n = blockIdx.x >> 3;
    int tid  = threadIdx.x;
    int wid  = tid >> 6;
    int lane = tid & 63;
    int col  = lane >> 4;
    unsigned laneoff = (unsigned)lane * 8;       // bf16 elems

    const float* roi = rois + n * 5;
    int   b  = (int)roi[0];
    float x1 = roi[1] * SPATIAL_SCALE;
    float y1 = roi[2] * SPATIAL_SCALE;
    float x2 = roi[3] * SPATIAL_SCALE;
    float y2 = roi[4] * SPATIAL_SCALE;
    float roi_w = fmaxf(x2 - x1, 1.0f);
    float roi_h = fmaxf(y2 - y1, 1.0f);
    float bin_w = roi_w * (1.0f / PW);
    float bin_h = roi_h * (1.0f / PH);
    float hbw = 0.5f * bin_w, hbh = 0.5f * bin_h;
    float xq = x1 + 0.5f * hbw;
    float yq = y1 + 0.5f * hbh;

    const __hip_bfloat16* slab = Tb + (size_t)((b * NXCD + g) * (HH * WW)) * CG;

    // ---- Phase 1: per-bin params, computed once per block ----
    if (tid < NPOS) {
        int m  = tid;
        int ph = m / 7;
        int pw = m - ph * 7;
        // y: 2 samples -> 3-row window, weight-0 clamp for row2
        float yc0 = fmaf((float)ph, bin_h, yq);
        float yc1 = yc0 + hbh;
        float vy0 = (yc0 >= -1.0f && yc0 <= (float)HH) ? 1.0f : 0.0f;
        float vy1 = (yc1 >= -1.0f && yc1 <= (float)HH) ? 1.0f : 0.0f;
        float ycl0 = fminf(fmaxf(yc0, 0.0f), (float)(HH - 1));
        float ycl1 = fminf(fmaxf(yc1, 0.0f), (float)(HH - 1));
        int yl0 = min(max((int)floorf(ycl0), 0), HH - 2);
        int yl1 = min(max((int)floorf(ycl1), 0), HH - 2);
        float ly0 = ycl0 - (float)yl0, hy0 = 1.0f - ly0;
        float ly1 = ycl1 - (float)yl1, hy1 = 1.0f - ly1;
        float wy0 = 0.25f * vy0 * hy0;
        float wy1 = 0.25f * vy0 * ly0;
        float wy2 = 0.25f * vy1 * hy1;
        float wy3 = 0.25f * vy1 * ly1;
        int q = yl1 - yl0;
        float wr0 = wy0 + ((q == 0) ? wy2 : 0.0f);
        float wr1 = wy1 + ((q == 0) ? wy3 : wy2);
        float wr2 = (q == 0) ? 0.0f : wy3;
        int r2 = min(yl0 + 2, HH - 1);           // clamped; wr2==0 when clamped
        // x: 2 samples; 4-col window base xw covers all taps
        float xc0 = fmaf((float)pw, bin_w, xq);
        float xc1 = xc0 + hbw;
        float vx0 = (xc0 >= -1.0f && xc0 <= (float)WW) ? 1.0f : 0.0f;
        float vx1 = (xc1 >= -1.0f && xc1 <= (float)WW) ? 1.0f : 0.0f;
        float xcl0 = fminf(fmaxf(xc0, 0.0f), (float)(WW - 1));
        float xcl1 = fminf(fmaxf(xc1, 0.0f), (float)(WW - 1));
        int xl0 = min(max((int)floorf(xcl0), 0), WW - 2);
        int xl1 = min(max((int)floorf(xcl1), 0), WW - 2);
        float lx0 = xcl0 - (float)xl0, hx0 = 1.0f - lx0;
        float lx1 = xcl1 - (float)xl1, hx1 = 1.0f - lx1;
        int xw = min(xl0, WW - 4);
        int p0 = xl0 - xw;                       // {0,1,2}
        int p1 = xl1 - xw;                       // p1+1 <= 3
        float u0 = vx0 * ((p0 == 0) ? hx0 : 0.0f) + vx1 * ((p1 == 0) ? hx1 : 0.0f);
        float u1 = vx0 * ((p0 == 1) ? hx0 : ((p0 == 0) ? lx0 : 0.0f))
                 + vx1 * ((p1 == 1) ? hx1 : ((p1 == 0) ? lx1 : 0.0f));
        float u2 = vx0 * ((p0 == 2) ? hx0 : ((p0 == 1) ? lx0 : 0.0f))
                 + vx1 * ((p1 == 2) ? hx1 : ((p1 == 1) ? lx1 : 0.0f));
        float u3 = vx0 * ((p0 + 1 == 3) ? lx0 : 0.0f)
                 + vx1 * ((p1 + 1 == 3) ? lx1 : 0.0f);
        int pb = m * 12;
        prm[pb + 0] = wr0;
        prm[pb + 1] = wr1;
        prm[pb + 2] = wr2;
        prm[pb + 3] = u0;
        prm[pb + 4] = u1;
        prm[pb + 5] = u2;
        prm[pb + 6] = u3;
        prm[pb + 7] = __uint_as_float((unsigned)((yl0 * WW + xw) * CG));
        prm[pb + 8] = __uint_as_float((unsigned)((r2 * WW + xw) * CG));
    }
    __syncthreads();

    // ---- Phase 2: main loop ----
    int nb = (wid == 0) ? 13 : 12;               // bins m = wid + 4k < 49
    for (int k = 0; k < nb; ++k) {
        int m  = wid + 4 * k;
        int pb = m * 12;
        float wr0 = prm[pb + 0];
        float wr1 = prm[pb + 1];
        float wr2 = prm[pb + 2];
        float uc  = prm[pb + 3 + col];
        unsigned o0 = __float_as_uint(prm[pb + 7]) + laneoff;
        unsigned o2 = __float_as_uint(prm[pb + 8]) + laneoff;

        u4v a0 = *(const u4v*)(slab + o0);
        u4v a1 = *(const u4v*)(slab + o0 + WW * CG);
        u4v a2 = *(const u4v*)(slab + o2);

        float wa0 = wr0 * uc, wa1 = wr1 * uc, wa2 = wr2 * uc;
        float r[8];
        #pragma unroll
        for (int p = 0; p < 4; ++p) {
            float l0 = __uint_as_float(a0[p] << 16);
            float h0 = __uint_as_float(a0[p] & 0xffff0000u);
            float l1 = __uint_as_float(a1[p] << 16);
            float h1 = __uint_as_float(a1[p] & 0xffff0000u);
            float l2 = __uint_as_float(a2[p] << 16);
            float h2 = __uint_as_float(a2[p] & 0xffff0000u);
            r[2 * p]     = fmaf(wa2, l2, fmaf(wa1, l1, wa0 * l0));
            r[2 * p + 1] = fmaf(wa2, h2, fmaf(wa1, h1, wa0 * h0));
        }
        #pragma unroll
        for (int j = 0; j < 8; ++j) r[j] += __shfl_xor(r[j], 16);
        #pragma unroll
        for (int j = 0; j < 8; ++j) r[j] += __shfl_xor(r[j], 32);

        if (lane < 16) {
            // phys = ch*49 + m + 4*(ch>>4), ch = lane*8+j -> 2-way banks (free)
            int idx = lane * 392 + m + 4 * (lane >> 1);
            #pragma unroll
            for (int j = 0; j < 8; ++j) { so[idx] = r[j]; idx += 49; }
        }
    }
    __syncthreads();

    // ---- Phase 3: coalesced b128 writeback (swizzle-aware) ----
    unsigned obase = (unsigned)(n * C_TOTAL + g * CG) * NPOS;
    f4a* dst = (f4a*)(out + obase);
    const f4a* src = (const f4a*)so;
    #pragma unroll
    for (int k2 = 0; k2 < 6; ++k2) {
        int t = k2 * 256 + tid;
        dst[t] = src[t + t / 196];               // shift constant within each f4
    }
    if (tid < 32) {
        int t = 1536 + tid;
        dst[t] = src[t + t / 196];
    }
}

// ---- Fallback (fp32 direct, ~R7) if workspace too small --------------------
__global__ __launch_bounds__(256) void roi_align_fallback(
    const float* __restrict__ data, const float* __restrict__ rois,
    float* __restrict__ out, int H, int W, int N)
{
    __shared__ __align__(16) float so[64 * NPOS];
    int i   = blockIdx.x;
    int xcd = i & (NXCD - 1);
    int j   = i >> 3;
    int scl = (j >= N) ? 1 : 0;
    int n   = j - scl * N;
    int superchunk = xcd * 2 + scl;
    int t = threadIdx.x;
    bool active = (t < 5 * NPOS);
    int tt = active ? t : 0;
    int s  = tt % NPOS;
    int g  = tt / NPOS;
    int cbase = g * 13;
    int cnt = (g < 4) ? 13 : 12;
    int pw = s % PW;
    int ph = s / PW;
    if (active) {
        const float* roi = rois + n * 5;
        int   b  = (int)roi[0];
        float x1 = roi[1] * SPATIAL_SCALE, y1 = roi[2] * SPATIAL_SCALE;
        float x2 = roi[3] * SPATIAL_SCALE, y2 = roi[4] * SPATIAL_SCALE;
        float roi_w = fmaxf(x2 - x1, 1.0f), roi_h = fmaxf(y2 - y1, 1.0f);
        float bin_w = roi_w * (1.0f / PW), bin_h = roi_h * (1.0f / PH);
        float xc0 = x1 + ((float)(pw * 2 + 0) + 0.5f) * bin_w * 0.5f;
        float xc1 = x1 + ((float)(pw * 2 + 1) + 0.5f) * bin_w * 0.5f;
        float vx0 = (xc0 >= -1.0f && xc0 <= (float)W) ? 1.0f : 0.0f;
        float vx1 = (xc1 >= -1.0f && xc1 <= (float)W) ? 1.0f : 0.0f;
        float xcl0 = fminf(fmaxf(xc0, 0.0f), (float)(W - 1));
        float xcl1 = fminf(fmaxf(xc1, 0.0f), (float)(W - 1));
        int xl0 = min(max((int)floorf(xcl0), 0), W - 2);
        int xl1 = min(max((int)floorf(xcl1), 0), W - 2);
        float lx0 = xcl0 - (float)xl0, hx0 = 1.0f - lx0;
        float lx1 = xcl1 - (float)xl1, hx1 = 1.0f - lx1;
        int xb = min(xl0 & ~1, W - 4);
        int p0 = xl0 - xb, p1 = xl1 - xb;
        float w4[4];
        #pragma unroll
        for (int k = 0; k < 4; ++k) {
            float a = (p0 == k) ? hx0 : ((p0 + 1 == k) ? lx0 : 0.0f);
            float c = (p1 == k) ? hx1 : ((p1 + 1 == k) ? lx1 : 0.0f);
            w4[k] = vx0 * a + vx1 * c;
        }
        float yc0 = y1 + ((float)(ph * 2 + 0) + 0.5f) * bin_h * 0.5f;
        float yc1 = y1 + ((float)(ph * 2 + 1) + 0.5f) * bin_h * 0.5f;
        float vy0 = (yc0 >= -1.0f && yc0 <= (float)H) ? 1.0f : 0.0f;
        float vy1 = (yc1 >= -1.0f && yc1 <= (float)H) ? 1.0f : 0.0f;
        float ycl0 = fminf(fmaxf(yc0, 0.0f), (float)(H - 1));
        float ycl1 = fminf(fmaxf(yc1, 0.0f), (float)(H - 1));
        int yl0 = min(max((int)floorf(ycl0), 0), H - 2);
        int yl1 = min(max((int)floorf(ycl1), 0), H - 2);
        float ly0 = ycl0 - (float)yl0, hy0 = 1.0f - ly0;
        float ly1 = ycl1 - (float)yl1, hy1 = 1.0f - ly1;
        float wy0 = 0.25f * vy0 * hy0, wy1 = 0.25f * vy0 * ly0;
        float wy2 = 0.25f * vy1 * hy1, wy3 = 0.25f * vy1 * ly1;
        int q = yl1 - yl0;
        float wr0 = wy0 + ((q == 0) ? wy2 : 0.0f);
        float wr1 = wy1 + ((q == 0) ? wy3 : wy2);
        float wr2 = (q == 0) ? 0.0f : wy3;
        int row0 = yl0;
        int row2 = min(yl0 + 2, H - 1);
        float wv[3][4];
        #pragma unroll
        for (int k = 0; k < 4; ++k) {
            wv[0][k] = wr0 * w4[k]; wv[1][k] = wr1 * w4[k]; wv[2][k] = wr2 * w4[k];
        }
        int c0 = superchunk * 64 + cbase;
        const int HW = H * W;
        unsigned slab = (unsigned)(b * C_TOTAL + c0) * (unsigned)HW;
        unsigned o0 = slab + (unsigned)(row0 * W + xb);
        unsigned o1 = o0 + (unsigned)W;
        unsigned o2 = slab + (unsigned)(row2 * W + xb);
        int ldsbase = cbase * NPOS + s;
        f4v a0 = *(const f4v*)(data + o0);
        f4v a1 = *(const f4v*)(data + o1);
        f4v a2 = *(const f4v*)(data + o2);
        int jj = 0;
        for (; jj < cnt - 1; ++jj) {
            o0 += HW; o1 += HW; o2 += HW;
            f4v b0 = *(const f4v*)(data + o0);
            f4v b1 = *(const f4v*)(data + o1);
            f4v b2 = *(const f4v*)(data + o2);
            float acc = wv[0][0]*a0.x + wv[0][1]*a0.y + wv[0][2]*a0.z + wv[0][3]*a0.w
                      + wv[1][0]*a1.x + wv[1][1]*a1.y + wv[1][2]*a1.z + wv[1][3]*a1.w
                      + wv[2][0]*a2.x + wv[2][1]*a2.y + wv[2][2]*a2.z + wv[2][3]*a2.w;
            so[ldsbase + jj * NPOS] = acc;
            a0 = b0; a1 = b1; a2 = b2;
        }
        float acc = wv[0][0]*a0.x + wv[0][1]*a0.y + wv[0][2]*a0.z + wv[0][3]*a0.w
                  + wv[1][0]*a1.x + wv[1][1]*a1.y + wv[1][2]*a1.z + wv[1][3]*a1.w
                  + wv[2][0]*a2.x + wv[2][1]*a2.y + wv[2][2]*a2.z + wv[2][3]*a2.w;
        so[ldsbase + jj * NPOS] = acc;
    }
    __syncthreads();
    unsigned base = (unsigned)(n * C_TOTAL + superchunk * 64) * NPOS;
    f4a* dst = (f4a*)(out + base);
    const f4a* src = (const f4a*)so;
    int tid = threadIdx.x;
    dst[tid] = src[tid];
    dst[256 + tid] = src[256 + tid];
    dst[512 + tid] = src[512 + tid];
    if (tid < 16) dst[768 + tid] = src[768 + tid];
}

extern "C" void kernel_launch(void* const* d_in, const int* in_sizes, int n_in,
                              void* d_out, int out_size, void* d_ws, size_t ws_size,
                              hipStream_t stream) {
    const float* data = (const float*)d_in[0];
    const float* rois = (const float*)d_in[1];
    float* out = (float*)d_out;
    const int N = in_sizes[1] / 5;

    if (ws_size >= TB_BYTES) {
        __hip_bfloat16* Tb = (__hip_bfloat16*)d_ws;
        transpose_bf16_kernel<<<2 * HH * NXCD, 256, 0, stream>>>(data, Tb);
        roi_bf16_kernel<<<N * NXCD, 256, 0, stream>>>(Tb, rois, out, N);
    } else {
        roi_align_fallback<<<N * 16, 256, 0, stream>>>(data, rois, out, HH, WW, N);
    }
}

// Round 12
// 62.378 us; speedup vs baseline: 1.1281x; 1.0450x over previous
//
#include <hip/hip_runtime.h>
#include <hip/hip_bf16.h>

#define SPATIAL_SCALE 0.0625f
#define PH 7
#define PW 7
#define C_TOTAL 1024
#define NXCD 8
#define NPOS 49
#define HH 50
#define WW 50
#define HWSZ 2500
#define TB_BYTES (2ULL * C_TOTAL * HWSZ * 2ULL)   // 10,240,000 B

typedef short bf16x8 __attribute__((ext_vector_type(8)));
typedef float f32x16 __attribute__((ext_vector_type(16)));
typedef float f4a __attribute__((ext_vector_type(4), aligned(16)));
typedef float f4v __attribute__((ext_vector_type(4), aligned(8)));
typedef unsigned int u4v __attribute__((ext_vector_type(4), aligned(16)));
typedef unsigned short us8v __attribute__((ext_vector_type(8), aligned(16)));

// ---- Kernel 1: elementwise fp32 -> bf16 (layout preserved: NCHW) ----------
__global__ __launch_bounds__(256) void cast_bf16_kernel(
    const float* __restrict__ in, __hip_bfloat16* __restrict__ Tb, int total8)
{
    int t = blockIdx.x * 256 + threadIdx.x;
    if (t >= total8) return;
    const f4a* p = (const f4a*)(in + (size_t)t * 8);
    f4a v0 = p[0], v1 = p[1];
    us8v o;
    __hip_bfloat16 h;
    h = __float2bfloat16(v0.x); o[0] = *(unsigned short*)&h;
    h = __float2bfloat16(v0.y); o[1] = *(unsigned short*)&h;
    h = __float2bfloat16(v0.z); o[2] = *(unsigned short*)&h;
    h = __float2bfloat16(v0.w); o[3] = *(unsigned short*)&h;
    h = __float2bfloat16(v1.x); o[4] = *(unsigned short*)&h;
    h = __float2bfloat16(v1.y); o[5] = *(unsigned short*)&h;
    h = __float2bfloat16(v1.z); o[6] = *(unsigned short*)&h;
    h = __float2bfloat16(v1.w); o[7] = *(unsigned short*)&h;
    *(us8v*)((unsigned short*)Tb + (size_t)t * 8) = o;
}

// ---- Kernel 2: ROI align as MFMA GEMM: out[bin][ch] = W[bin][tap]*V[tap][ch]
// Block = (roi n, slab g, half h): 64 channels. blockIdx&7 = g -> XCD pin.
// W: [52 bins][K=256 taps] bf16 LDS, XOR-swizzled rows, x4-scaled weights.
// V: [64 ch][64 taps] bf16 LDS per 4-row chunk, rotation-swizzled rows.
// 4 waves = (Mtile 0/1) x (Ntile 0/1), mfma_f32_32x32x16_bf16 over K.
// C -> [64][52] f32 LDS (aligned f4) -> coalesced writeback with x0.25.
__global__ __launch_bounds__(256) void roi_mfma_kernel(
    const __hip_bfloat16* __restrict__ Tbh,
    const float* __restrict__ rois,
    float* __restrict__ out, int N)
{
    __shared__ __align__(16) char ldsb[48128];
    short* Wl = (short*)ldsb;                    // 52*256 = 13312 shorts (26624B)
    short* Vl = (short*)(ldsb + 26624);          // 64*64  = 4096 shorts  (8192B)
    unsigned int* Vu = (unsigned int*)(ldsb + 26624);
    float* sol = (float*)(ldsb + 34816);         // 64*52  = 3328 floats  (13312B)

    const unsigned short* Tb = (const unsigned short*)Tbh;

    int g   = blockIdx.x & (NXCD - 1);
    int h   = (blockIdx.x >> 3) & 1;
    int n   = blockIdx.x >> 4;
    int tid = threadIdx.x;
    int wid = tid >> 6;
    int lane = tid & 63;
    int lane31 = lane & 31;
    int hi = lane >> 5;

    const float* roi = rois + n * 5;
    int   b  = (int)roi[0];
    float x1 = roi[1] * SPATIAL_SCALE;
    float y1 = roi[2] * SPATIAL_SCALE;
    float x2 = roi[3] * SPATIAL_SCALE;
    float y2 = roi[4] * SPATIAL_SCALE;
    float roi_w = fmaxf(x2 - x1, 1.0f);
    float roi_h = fmaxf(y2 - y1, 1.0f);
    float bin_w = roi_w * (1.0f / PW);
    float bin_h = roi_h * (1.0f / PH);
    float hbw = 0.5f * bin_w, hbh = 0.5f * bin_h;
    float xq = x1 + 0.5f * hbw;                  // xc0(pw) = pw*bin_w + xq
    float yq = y1 + 0.5f * hbh;

    // ---- window base rb/cb (all threads, redundant) ----
    int minr = 48, minc = 48, maxr0 = 0;
    #pragma unroll
    for (int i = 0; i < 7; ++i) {
        float yc0 = fmaf((float)i, bin_h, yq);
        float ycl0 = fminf(fmaxf(yc0, 0.0f), 49.0f);
        int yl0 = min(max((int)floorf(ycl0), 0), 48);
        minr = min(minr, yl0);
        maxr0 = max(maxr0, yl0);
        float xc0 = fmaf((float)i, bin_w, xq);
        float xcl0 = fminf(fmaxf(xc0, 0.0f), 49.0f);
        int xl0 = min(max((int)floorf(xcl0), 0), 48);
        minc = min(minc, xl0);
    }
    int rb = min(minr, 34);
    int cb = min(minc, 34) & ~1;                 // even -> 4B-aligned V loads
    int maxr = min(maxr0 + 2, 49);
    int nch = ((maxr - rb) >> 2) + 1;            // 1..4 chunks of 4 rows

    // ---- zero W ----
    u4v zero4 = {0u, 0u, 0u, 0u};
    u4v* Wz = (u4v*)ldsb;
    #pragma unroll
    for (int i = 0; i < 7; ++i) {
        int idx = tid + i * 256;
        if (idx < 1664) Wz[idx] = zero4;
    }
    __syncthreads();

    // ---- build W: 49 bins x 9 (3 rows x 3 cols) slots, weights x4-scaled ----
    for (int idx = tid; idx < 441; idx += 256) {
        int bin  = idx / 9;
        int slot = idx - bin * 9;
        int sr = slot / 3, sc = slot - sr * 3;
        int ph = bin / 7, pw = bin - ph * 7;
        // y params
        float yc0 = fmaf((float)ph, bin_h, yq);
        float yc1 = yc0 + hbh;
        float vy0 = (yc0 >= -1.0f && yc0 <= 50.0f) ? 1.0f : 0.0f;
        float vy1 = (yc1 >= -1.0f && yc1 <= 50.0f) ? 1.0f : 0.0f;
        float ycl0 = fminf(fmaxf(yc0, 0.0f), 49.0f);
        float ycl1 = fminf(fmaxf(yc1, 0.0f), 49.0f);
        int yl0 = min(max((int)floorf(ycl0), 0), 48);
        int yl1 = min(max((int)floorf(ycl1), 0), 48);
        float ly0 = ycl0 - (float)yl0, hy0 = 1.0f - ly0;
        float ly1 = ycl1 - (float)yl1, hy1 = 1.0f - ly1;
        int q = yl1 - yl0;
        float wy0 = vy0 * hy0, wy1 = vy0 * ly0;
        float wy2 = vy1 * hy1, wy3 = vy1 * ly1;
        float wr0 = wy0 + ((q == 0) ? wy2 : 0.0f);
        float wr1 = wy1 + ((q == 0) ? wy3 : wy2);
        float wr2 = (q == 0) ? 0.0f : wy3;
        float wrs = (sr == 0) ? wr0 : ((sr == 1) ? wr1 : wr2);
        int r = yl0 + sr;
        // x params
        float xc0 = fmaf((float)pw, bin_w, xq);
        float xc1 = xc0 + hbw;
        float vx0 = (xc0 >= -1.0f && xc0 <= 50.0f) ? 1.0f : 0.0f;
        float vx1 = (xc1 >= -1.0f && xc1 <= 50.0f) ? 1.0f : 0.0f;
        float xcl0 = fminf(fmaxf(xc0, 0.0f), 49.0f);
        float xcl1 = fminf(fmaxf(xc1, 0.0f), 49.0f);
        int xl0 = min(max((int)floorf(xcl0), 0), 48);
        int xl1 = min(max((int)floorf(xcl1), 0), 48);
        float lx0 = xcl0 - (float)xl0, hx0 = 1.0f - lx0;
        float lx1 = xcl1 - (float)xl1, hx1 = 1.0f - lx1;
        int dx = xl1 - xl0;
        float u0 = vx0 * hx0 + ((dx == 0) ? vx1 * hx1 : 0.0f);
        float u1 = vx0 * lx0 + ((dx == 0) ? vx1 * lx1 : vx1 * hx1);
        float u2 = (dx == 0) ? 0.0f : vx1 * lx1;
        float ucs = (sc == 0) ? u0 : ((sc == 1) ? u1 : u2);
        int c = xl0 + sc;
        float w = wrs * ucs;                     // in [0,1]; x0.25 applied at end
        int rr = r - rb, cc = c - cb;
        if (((unsigned)rr < 16u) && ((unsigned)cc < 16u)) {
            int tap = rr * 16 + cc;
            __hip_bfloat16 hb = __float2bfloat16(w);
            Wl[bin * 256 + (tap ^ ((bin & 15) << 3))] = *(short*)&hb;
        }
    }

    // ---- MFMA main loop ----
    int m  = wid >> 1;                           // Mtile 0/1 (bins 0-31 / 32-63)
    int nt = wid & 1;                            // Ntile 0/1 (ch 0-31 / 32-63)
    int bin  = m * 32 + lane31;
    int wrow = bin * 256;
    int wsw  = (bin & 15) << 3;
    int ch   = nt * 32 + lane31;
    int hi8  = hi * 8;
    int tbbase = (b * C_TOTAL + g * 128 + h * 64) * HWSZ;

    f32x16 acc = {};
    for (int chunk = 0; chunk < nch; ++chunk) {
        // load V chunk: 4 rows x 16 cols x 64 ch (bf16), rotation-swizzled LDS
        int rbase = rb + chunk * 4;
        #pragma unroll
        for (int it = 0; it < 8; ++it) {
            int idx = tid + it * 256;
            int vch = idx >> 5;
            int rem = idx & 31;
            int rl = rem >> 3;
            int p2 = rem & 7;
            unsigned int v = *(const unsigned int*)
                (Tb + tbbase + vch * HWSZ + (rbase + rl) * WW + cb + 2 * p2);
            int t = rl * 16 + 2 * p2;
            Vu[(vch * 64 + ((t + vch * 8) & 63)) >> 1] = v;
        }
        __syncthreads();
        #pragma unroll
        for (int kl = 0; kl < 4; ++kl) {
            int kk = chunk * 4 + kl;
            bf16x8 av = *(const bf16x8*)&Wl[wrow + ((kk * 16 + hi8) ^ wsw)];
            bf16x8 bv = *(const bf16x8*)&Vl[ch * 64 + ((kl * 16 + hi8 + ch * 8) & 63)];
            acc = __builtin_amdgcn_mfma_f32_32x32x16_bf16(av, bv, acc, 0, 0, 0);
        }
        __syncthreads();
    }

    // ---- C -> sol: lane owns ch, 4 groups of 4 consecutive bins ----
    #pragma unroll
    for (int q = 0; q < 4; ++q) {
        int bin0 = m * 32 + 8 * q + 4 * hi;
        if (bin0 <= 48) {
            f4a v; v.x = acc[4*q]; v.y = acc[4*q+1]; v.z = acc[4*q+2]; v.w = acc[4*q+3];
            *(f4a*)&sol[ch * 52 + bin0] = v;
        }
    }
    __syncthreads();

    // ---- coalesced writeback (x0.25 mean+validity scale restore) ----
    int outbase = (n * C_TOTAL + g * 128 + h * 64) * NPOS;
    #pragma unroll
    for (int k2 = 0; k2 < 4; ++k2) {
        int t = k2 * 256 + tid;
        if (t < 784) {
            f4a o;
            #pragma unroll
            for (int i2 = 0; i2 < 4; ++i2) {
                int f = 4 * t + i2;
                int fch = f / 49;
                int fbin = f - fch * 49;
                o[i2] = sol[fch * 52 + fbin] * 0.25f;
            }
            *(f4a*)(out + outbase + 4 * t) = o;
        }
    }
}

// ---- Fallback (fp32 direct, ~R7) if workspace too small --------------------
__global__ __launch_bounds__(256) void roi_align_fallback(
    const float* __restrict__ data, const float* __restrict__ rois,
    float* __restrict__ out, int H, int W, int N)
{
    __shared__ __align__(16) float so[64 * NPOS];
    int i   = blockIdx.x;
    int xcd = i & (NXCD - 1);
    int j   = i >> 3;
    int scl = (j >= N) ? 1 : 0;
    int n   = j - scl * N;
    int superchunk = xcd * 2 + scl;
    int t = threadIdx.x;
    bool active = (t < 5 * NPOS);
    int tt = active ? t : 0;
    int s  = tt % NPOS;
    int g  = tt / NPOS;
    int cbase = g * 13;
    int cnt = (g < 4) ? 13 : 12;
    int pw = s % PW;
    int ph = s / PW;
    if (active) {
        const float* roi = rois + n * 5;
        int   b  = (int)roi[0];
        float x1 = roi[1] * SPATIAL_SCALE, y1 = roi[2] * SPATIAL_SCALE;
        float x2 = roi[3] * SPATIAL_SCALE, y2 = roi[4] * SPATIAL_SCALE;
        float roi_w = fmaxf(x2 - x1, 1.0f), roi_h = fmaxf(y2 - y1, 1.0f);
        float bin_w = roi_w * (1.0f / PW), bin_h = roi_h * (1.0f / PH);
        float xc0 = x1 + ((float)(pw * 2 + 0) + 0.5f) * bin_w * 0.5f;
        float xc1 = x1 + ((float)(pw * 2 + 1) + 0.5f) * bin_w * 0.5f;
        float vx0 = (xc0 >= -1.0f && xc0 <= (float)W) ? 1.0f : 0.0f;
        float vx1 = (xc1 >= -1.0f && xc1 <= (float)W) ? 1.0f : 0.0f;
        float xcl0 = fminf(fmaxf(xc0, 0.0f), (float)(W - 1));
        float xcl1 = fminf(fmaxf(xc1, 0.0f), (float)(W - 1));
        int xl0 = min(max((int)floorf(xcl0), 0), W - 2);
        int xl1 = min(max((int)floorf(xcl1), 0), W - 2);
        float lx0 = xcl0 - (float)xl0, hx0 = 1.0f - lx0;
        float lx1 = xcl1 - (float)xl1, hx1 = 1.0f - lx1;
        int xb = min(xl0 & ~1, W - 4);
        int p0 = xl0 - xb, p1 = xl1 - xb;
        float w4[4];
        #pragma unroll
        for (int k = 0; k < 4; ++k) {
            float a = (p0 == k) ? hx0 : ((p0 + 1 == k) ? lx0 : 0.0f);
            float c = (p1 == k) ? hx1 : ((p1 + 1 == k) ? lx1 : 0.0f);
            w4[k] = vx0 * a + vx1 * c;
        }
        float yc0 = y1 + ((float)(ph * 2 + 0) + 0.5f) * bin_h * 0.5f;
        float yc1 = y1 + ((float)(ph * 2 + 1) + 0.5f) * bin_h * 0.5f;
        float vy0 = (yc0 >= -1.0f && yc0 <= (float)H) ? 1.0f : 0.0f;
        float vy1 = (yc1 >= -1.0f && yc1 <= (float)H) ? 1.0f : 0.0f;
        float ycl0 = fminf(fmaxf(yc0, 0.0f), (float)(H - 1));
        float ycl1 = fminf(fmaxf(yc1, 0.0f), (float)(H - 1));
        int yl0 = min(max((int)floorf(ycl0), 0), H - 2);
        int yl1 = min(max((int)floorf(ycl1), 0), H - 2);
        float ly0 = ycl0 - (float)yl0, hy0 = 1.0f - ly0;
        float ly1 = ycl1 - (float)yl1, hy1 = 1.0f - ly1;
        float wy0 = 0.25f * vy0 * hy0, wy1 = 0.25f * vy0 * ly0;
        float wy2 = 0.25f * vy1 * hy1, wy3 = 0.25f * vy1 * ly1;
        int q = yl1 - yl0;
        float wr0 = wy0 + ((q == 0) ? wy2 : 0.0f);
        float wr1 = wy1 + ((q == 0) ? wy3 : wy2);
        float wr2 = (q == 0) ? 0.0f : wy3;
        int row0 = yl0;
        int row2 = min(yl0 + 2, H - 1);
        float wv[3][4];
        #pragma unroll
        for (int k = 0; k < 4; ++k) {
            wv[0][k] = wr0 * w4[k]; wv[1][k] = wr1 * w4[k]; wv[2][k] = wr2 * w4[k];
        }
        int c0 = superchunk * 64 + cbase;
        const int HW = H * W;
        unsigned slab = (unsigned)(b * C_TOTAL + c0) * (unsigned)HW;
        unsigned o0 = slab + (unsigned)(row0 * W + xb);
        unsigned o1 = o0 + (unsigned)W;
        unsigned o2 = slab + (unsigned)(row2 * W + xb);
        int ldsbase = cbase * NPOS + s;
        f4v a0 = *(const f4v*)(data + o0);
        f4v a1 = *(const f4v*)(data + o1);
        f4v a2 = *(const f4v*)(data + o2);
        int jj = 0;
        for (; jj < cnt - 1; ++jj) {
            o0 += HW; o1 += HW; o2 += HW;
            f4v b0 = *(const f4v*)(data + o0);
            f4v b1 = *(const f4v*)(data + o1);
            f4v b2 = *(const f4v*)(data + o2);
            float acc = wv[0][0]*a0.x + wv[0][1]*a0.y + wv[0][2]*a0.z + wv[0][3]*a0.w
                      + wv[1][0]*a1.x + wv[1][1]*a1.y + wv[1][2]*a1.z + wv[1][3]*a1.w
                      + wv[2][0]*a2.x + wv[2][1]*a2.y + wv[2][2]*a2.z + wv[2][3]*a2.w;
            so[ldsbase + jj * NPOS] = acc;
            a0 = b0; a1 = b1; a2 = b2;
        }
        float acc = wv[0][0]*a0.x + wv[0][1]*a0.y + wv[0][2]*a0.z + wv[0][3]*a0.w
                  + wv[1][0]*a1.x + wv[1][1]*a1.y + wv[1][2]*a1.z + wv[1][3]*a1.w
                  + wv[2][0]*a2.x + wv[2][1]*a2.y + wv[2][2]*a2.z + wv[2][3]*a2.w;
        so[ldsbase + jj * NPOS] = acc;
    }
    __syncthreads();
    unsigned base = (unsigned)(n * C_TOTAL + superchunk * 64) * NPOS;
    f4a* dst = (f4a*)(out + base);
    const f4a* src = (const f4a*)so;
    int tid = threadIdx.x;
    dst[tid] = src[tid];
    dst[256 + tid] = src[256 + tid];
    dst[512 + tid] = src[512 + tid];
    if (tid < 16) dst[768 + tid] = src[768 + tid];
}

extern "C" void kernel_launch(void* const* d_in, const int* in_sizes, int n_in,
                              void* d_out, int out_size, void* d_ws, size_t ws_size,
                              hipStream_t stream) {
    const float* data = (const float*)d_in[0];
    const float* rois = (const float*)d_in[1];
    float* out = (float*)d_out;
    const int N = in_sizes[1] / 5;
    const int total = in_sizes[0];               // B*C*H*W = 5,120,000

    if (ws_size >= TB_BYTES) {
        __hip_bfloat16* Tb = (__hip_bfloat16*)d_ws;
        int total8 = total / 8;
        cast_bf16_kernel<<<(total8 + 255) / 256, 256, 0, stream>>>(data, Tb, total8);
        roi_mfma_kernel<<<N * 16, 256, 0, stream>>>(Tb, rois, out, N);
    } else {
        roi_align_fallback<<<N * 16, 256, 0, stream>>>(data, rois, out, HH, WW, N);
    }
}

// Round 13
// 46.632 us; speedup vs baseline: 1.5091x; 1.3377x over previous
//
#include <hip/hip_runtime.h>
#include <hip/hip_bf16.h>

#define SPATIAL_SCALE 0.0625f
#define PH 7
#define PW 7
#define C_TOTAL 1024
#define NXCD 8
#define NPOS 49
#define CG 128
#define HH 50
#define WW 50
#define TB_BYTES (2ULL * NXCD * HH * WW * CG * 2ULL)   // 10,240,000 B (bf16)

typedef short bf16x8 __attribute__((ext_vector_type(8)));
typedef float f32x16 __attribute__((ext_vector_type(16)));
typedef float f4a __attribute__((ext_vector_type(4), aligned(16)));
typedef float f4v __attribute__((ext_vector_type(4), aligned(8)));
typedef unsigned int u4v __attribute__((ext_vector_type(4), aligned(16)));
typedef unsigned int u2v __attribute__((ext_vector_type(2), aligned(8)));

// ---- Kernel 1: NCHW fp32 -> [b][g][y][x][c128] bf16 channels-last ----------
// (R10's proven transpose, ~2.7us). bid&7 = g -> slab written by its own XCD.
__global__ __launch_bounds__(256) void transpose_bf16_kernel(
    const float* __restrict__ in, __hip_bfloat16* __restrict__ Tb)
{
    __shared__ float lds[CG][WW + 1];
    int bid = blockIdx.x;            // (b*50 + y)*8 + g
    int g = bid & 7;
    int r = bid >> 3;
    int y = r % HH;
    int b = r / HH;
    int tid = threadIdx.x;

    const float* src = in + (size_t)(b * C_TOTAL + g * CG) * (HH * WW) + y * WW;
    #pragma unroll
    for (int it = 0; it < 25; ++it) {        // 6400 = 128c x 50x
        int idx = it * 256 + tid;
        int c = idx / WW;
        int x = idx - c * WW;
        lds[c][x] = src[c * (HH * WW) + x];
    }
    __syncthreads();
    __hip_bfloat16* dst = Tb + (size_t)((b * NXCD + g) * (HH * WW) + y * WW) * CG;
    #pragma unroll
    for (int it = 0; it < 25; ++it) {
        int idx = it * 256 + tid;
        int x = idx >> 7;                    // 0..49
        int c = idx & 127;
        dst[x * CG + c] = __float2bfloat16(lds[c][x]);
    }
}

// ---- Kernel 2: ROI align as MFMA GEMM with coalesced channels-last staging -
// Block = (roi n, slab g): 128 ch, 4 waves. blockIdx&7 = g -> XCD pin.
// out[bin][ch] = sum_tap W[bin][tap] * V[tap][ch]; taps = 16x16 window,
// K chunked 64 (4 rows) at a time, chunk count nch limited to the row span.
// W: [52][256] bf16 LDS, XOR-swizzled (R12-proven); built factorized from
// 7 y-params + 7 x-params. V: [128ch][64tap] bf16 LDS, segment-rotation
// swizzled; staged via coalesced dwordx2 loads + register repack + b128.
// Wave wid: Mtile=wid>>1 (bins), Ntiles {wid&1, +2} (ch), 2 accumulators.
// sol (f32 [128][52]) reuses the W region; coalesced x0.25 writeback.
__global__ __launch_bounds__(256) void roi_mfma_kernel(
    const unsigned int* __restrict__ Tw,   // channels-last bf16 viewed as u32
    const float* __restrict__ rois,
    float* __restrict__ out, int N)
{
    __shared__ __align__(16) char ldsb[43264];
    short* Wl  = (short*)ldsb;               // 52*256 shorts = 26624B
    float* sol = (float*)ldsb;               // 128*52 floats = 26624B (reuse)
    short* Vl  = (short*)(ldsb + 26624);     // 128*64 shorts = 16384B
    float* prm = (float*)(ldsb + 43008);     // 64 floats

    int g   = blockIdx.x & (NXCD - 1);
    int n   = blockIdx.x >> 3;
    int tid = threadIdx.x;
    int wid = tid >> 6, lane = tid & 63, lane31 = lane & 31, hi = lane >> 5;

    const float* roi = rois + n * 5;
    int   b  = (int)roi[0];
    float x1 = roi[1] * SPATIAL_SCALE;
    float y1 = roi[2] * SPATIAL_SCALE;
    float x2 = roi[3] * SPATIAL_SCALE;
    float y2 = roi[4] * SPATIAL_SCALE;
    float bin_w = fmaxf(x2 - x1, 1.0f) * (1.0f / 7.0f);
    float bin_h = fmaxf(y2 - y1, 1.0f) * (1.0f / 7.0f);
    float xq = x1 + 0.25f * bin_w;           // xc0(pw) = pw*bin_w + xq
    float yq = y1 + 0.25f * bin_h;

    // ---- Phase A: axis params (t0-6: y, t7-13: x) || zero W ----
    if (tid < 14) {
        bool isx = tid >= 7;
        int i = isx ? tid - 7 : tid;
        float step = isx ? bin_w : bin_h;
        float c0 = fmaf((float)i, step, isx ? xq : yq);
        float c1 = c0 + 0.5f * step;
        float v0 = (c0 >= -1.0f && c0 <= 50.0f) ? 1.0f : 0.0f;
        float v1 = (c1 >= -1.0f && c1 <= 50.0f) ? 1.0f : 0.0f;
        float cl0 = fminf(fmaxf(c0, 0.0f), 49.0f);
        float cl1 = fminf(fmaxf(c1, 0.0f), 49.0f);
        int l0 = min(max((int)floorf(cl0), 0), 48);
        int l1 = min(max((int)floorf(cl1), 0), 48);
        float f0 = cl0 - (float)l0, g0 = 1.0f - f0;
        float f1 = cl1 - (float)l1, g1 = 1.0f - f1;
        int dq = l1 - l0;                    // 0 or 1
        float w0 = v0 * g0 + ((dq == 0) ? v1 * g1 : 0.0f);
        float w1 = v0 * f0 + ((dq == 0) ? v1 * f1 : v1 * g1);
        float w2 = (dq == 0) ? 0.0f : v1 * f1;
        int base = (isx ? 28 : 0) + i * 4;
        prm[base + 0] = w0; prm[base + 1] = w1; prm[base + 2] = w2;
        prm[base + 3] = __int_as_float(l0);
    }
    {
        u4v z = {0u, 0u, 0u, 0u};
        u4v* Wz = (u4v*)ldsb;                // 26624B = 1664 u4v
        #pragma unroll
        for (int i = 0; i < 7; ++i) {
            int idx = tid + i * 256;
            if (idx < 1664) Wz[idx] = z;
        }
    }
    __syncthreads();

    // ---- window base (uniform, from prm) ----
    int minr = 48, maxr0 = 0, minc = 48;
    #pragma unroll
    for (int i = 0; i < 7; ++i) {
        int yl = __float_as_int(prm[i * 4 + 3]);
        int xl = __float_as_int(prm[28 + i * 4 + 3]);
        minr = min(minr, yl); maxr0 = max(maxr0, yl); minc = min(minc, xl);
    }
    int rb = min(minr, 34);
    int cb = min(minc, 34) & ~1;             // even -> 4B-aligned staging
    int nch = ((min(maxr0 + 2, 49) - rb) >> 2) + 1;   // 1..4 chunks

    // ---- W build: 441 slots, 2 LDS reads + mul + cvt each ----
    for (int idx = tid; idx < 441; idx += 256) {
        int bin  = idx / 9;
        int slot = idx - bin * 9;
        int sr = slot / 3, sc = slot - sr * 3;
        int ph = bin / 7, pw = bin - ph * 7;
        float w = prm[ph * 4 + sr] * prm[28 + pw * 4 + sc];
        int rr = __float_as_int(prm[ph * 4 + 3]) + sr - rb;
        int cc = __float_as_int(prm[28 + pw * 4 + 3]) + sc - cb;
        if (((unsigned)rr < 16u) && ((unsigned)cc < 16u)) {
            __hip_bfloat16 hb = __float2bfloat16(w);
            Wl[bin * 256 + ((rr * 16 + cc) ^ ((bin & 15) << 3))] = *(short*)&hb;
        }
    }
    __syncthreads();

    // ---- MFMA main loop ----
    int m    = wid >> 1;                     // Mtile: bins m*32..m*32+31
    int bin  = m * 32 + lane31;
    int wrow = bin * 256;
    int wsw  = (bin & 15) << 3;
    int ch0  = (wid & 1) * 32 + lane31;      // Ntile pair {ch0, ch0+64}
    int ch1  = ch0 + 64;
    int rot0 = ch0 >> 2, rot1 = ch1 >> 2;
    int cq   = tid & 31;                     // staging: u32-pair -> 4 channels
    int half = (tid >> 5) & 1;               // taps 0-7 / 8-15 within row
    int tg   = tid >> 6;                     // row 0..3 of chunk
    const unsigned int* slabU = Tw + (size_t)(b * NXCD + g) * (HH * WW * 64);

    f32x16 acc0 = {}, acc1 = {};
    for (int chunk = 0; chunk < nch; ++chunk) {
        int r0 = rb + chunk * 4 + tg;        // may exceed 49: reads land in
                                             // adjacent slab / 0xAA poison
                                             // (finite bf16) x W==0 -> safe
        const unsigned int* rp = slabU + (r0 * WW + cb + half * 8) * 64 + 2 * cq;
        u2v A0 = *(const u2v*)(rp);
        u2v A1 = *(const u2v*)(rp + 64);
        u2v A2 = *(const u2v*)(rp + 128);
        u2v A3 = *(const u2v*)(rp + 192);
        u2v A4 = *(const u2v*)(rp + 256);
        u2v A5 = *(const u2v*)(rp + 320);
        u2v A6 = *(const u2v*)(rp + 384);
        u2v A7 = *(const u2v*)(rp + 448);
        u4v lo0, hi0, lo1, hi1;
        lo0[0] = (A0[0] & 0xffffu) | (A1[0] << 16);
        lo0[1] = (A2[0] & 0xffffu) | (A3[0] << 16);
        lo0[2] = (A4[0] & 0xffffu) | (A5[0] << 16);
        lo0[3] = (A6[0] & 0xffffu) | (A7[0] << 16);
        hi0[0] = (A0[0] >> 16) | (A1[0] & 0xffff0000u);
        hi0[1] = (A2[0] >> 16) | (A3[0] & 0xffff0000u);
        hi0[2] = (A4[0] >> 16) | (A5[0] & 0xffff0000u);
        hi0[3] = (A6[0] >> 16) | (A7[0] & 0xffff0000u);
        lo1[0] = (A0[1] & 0xffffu) | (A1[1] << 16);
        lo1[1] = (A2[1] & 0xffffu) | (A3[1] << 16);
        lo1[2] = (A4[1] & 0xffffu) | (A5[1] << 16);
        lo1[3] = (A6[1] & 0xffffu) | (A7[1] << 16);
        hi1[0] = (A0[1] >> 16) | (A1[1] & 0xffff0000u);
        hi1[1] = (A2[1] >> 16) | (A3[1] & 0xffff0000u);
        hi1[2] = (A4[1] >> 16) | (A5[1] & 0xffff0000u);
        hi1[3] = (A6[1] >> 16) | (A7[1] & 0xffff0000u);
        int seg = tg * 2 + half;
        int chA = 4 * cq;
        int rotw = (seg + cq) & 7;           // rotate by ch>>2 (= cq)
        *(u4v*)&Vl[(chA    ) * 64 + rotw * 8] = lo0;
        *(u4v*)&Vl[(chA + 1) * 64 + rotw * 8] = hi0;
        *(u4v*)&Vl[(chA + 2) * 64 + rotw * 8] = lo1;
        *(u4v*)&Vl[(chA + 3) * 64 + rotw * 8] = hi1;
        __syncthreads();
        #pragma unroll
        for (int kl = 0; kl < 4; ++kl) {
            int kk = chunk * 4 + kl;
            bf16x8 av  = *(const bf16x8*)&Wl[wrow + ((kk * 16 + hi * 8) ^ wsw)];
            bf16x8 bv0 = *(const bf16x8*)&Vl[ch0 * 64 + (((kl * 2 + hi) + rot0) & 7) * 8];
            bf16x8 bv1 = *(const bf16x8*)&Vl[ch1 * 64 + (((kl * 2 + hi) + rot1) & 7) * 8];
            acc0 = __builtin_amdgcn_mfma_f32_32x32x16_bf16(av, bv0, acc0, 0, 0, 0);
            acc1 = __builtin_amdgcn_mfma_f32_32x32x16_bf16(av, bv1, acc1, 0, 0, 0);
        }
        __syncthreads();
    }

    // ---- C -> sol (reuses W region; all MFMA reads complete) ----
    #pragma unroll
    for (int q = 0; q < 4; ++q) {
        int bin0 = m * 32 + 8 * q + 4 * hi;  // C/D row = (reg&3)+8*(reg>>2)+4*hi
        if (bin0 <= 48) {
            f4a v0, v1;
            v0[0] = acc0[4*q]; v0[1] = acc0[4*q+1]; v0[2] = acc0[4*q+2]; v0[3] = acc0[4*q+3];
            v1[0] = acc1[4*q]; v1[1] = acc1[4*q+1]; v1[2] = acc1[4*q+2]; v1[3] = acc1[4*q+3];
            *(f4a*)&sol[ch0 * 52 + bin0] = v0;
            *(f4a*)&sol[ch1 * 52 + bin0] = v1;
        }
    }
    __syncthreads();

    // ---- coalesced writeback (x0.25 mean scale) ----
    int outbase = (n * C_TOTAL + g * CG) * NPOS;
    #pragma unroll
    for (int k2 = 0; k2 < 7; ++k2) {
        int t = k2 * 256 + tid;
        if (t < 1568) {                      // 128*49/4
            f4a o;
            #pragma unroll
            for (int i2 = 0; i2 < 4; ++i2) {
                int f = 4 * t + i2;
                int fch = f / 49;
                int fbin = f - fch * 49;
                o[i2] = sol[fch * 52 + fbin] * 0.25f;
            }
            *(f4a*)(out + outbase + 4 * t) = o;
        }
    }
}

// ---- Fallback (fp32 direct, ~R7) if workspace too small --------------------
__global__ __launch_bounds__(256) void roi_align_fallback(
    const float* __restrict__ data, const float* __restrict__ rois,
    float* __restrict__ out, int H, int W, int N)
{
    __shared__ __align__(16) float so[64 * NPOS];
    int i   = blockIdx.x;
    int xcd = i & (NXCD - 1);
    int j   = i >> 3;
    int scl = (j >= N) ? 1 : 0;
    int n   = j - scl * N;
    int superchunk = xcd * 2 + scl;
    int t = threadIdx.x;
    bool active = (t < 5 * NPOS);
    int tt = active ? t : 0;
    int s  = tt % NPOS;
    int g  = tt / NPOS;
    int cbase = g * 13;
    int cnt = (g < 4) ? 13 : 12;
    int pw = s % PW;
    int ph = s / PW;
    if (active) {
        const float* roi = rois + n * 5;
        int   b  = (int)roi[0];
        float x1 = roi[1] * SPATIAL_SCALE, y1 = roi[2] * SPATIAL_SCALE;
        float x2 = roi[3] * SPATIAL_SCALE, y2 = roi[4] * SPATIAL_SCALE;
        float roi_w = fmaxf(x2 - x1, 1.0f), roi_h = fmaxf(y2 - y1, 1.0f);
        float bin_w = roi_w * (1.0f / PW), bin_h = roi_h * (1.0f / PH);
        float xc0 = x1 + ((float)(pw * 2 + 0) + 0.5f) * bin_w * 0.5f;
        float xc1 = x1 + ((float)(pw * 2 + 1) + 0.5f) * bin_w * 0.5f;
        float vx0 = (xc0 >= -1.0f && xc0 <= (float)W) ? 1.0f : 0.0f;
        float vx1 = (xc1 >= -1.0f && xc1 <= (float)W) ? 1.0f : 0.0f;
        float xcl0 = fminf(fmaxf(xc0, 0.0f), (float)(W - 1));
        float xcl1 = fminf(fmaxf(xc1, 0.0f), (float)(W - 1));
        int xl0 = min(max((int)floorf(xcl0), 0), W - 2);
        int xl1 = min(max((int)floorf(xcl1), 0), W - 2);
        float lx0 = xcl0 - (float)xl0, hx0 = 1.0f - lx0;
        float lx1 = xcl1 - (float)xl1, hx1 = 1.0f - lx1;
        int xb = min(xl0 & ~1, W - 4);
        int p0 = xl0 - xb, p1 = xl1 - xb;
        float w4[4];
        #pragma unroll
        for (int k = 0; k < 4; ++k) {
            float a = (p0 == k) ? hx0 : ((p0 + 1 == k) ? lx0 : 0.0f);
            float c = (p1 == k) ? hx1 : ((p1 + 1 == k) ? lx1 : 0.0f);
            w4[k] = vx0 * a + vx1 * c;
        }
        float yc0 = y1 + ((float)(ph * 2 + 0) + 0.5f) * bin_h * 0.5f;
        float yc1 = y1 + ((float)(ph * 2 + 1) + 0.5f) * bin_h * 0.5f;
        float vy0 = (yc0 >= -1.0f && yc0 <= (float)H) ? 1.0f : 0.0f;
        float vy1 = (yc1 >= -1.0f && yc1 <= (float)H) ? 1.0f : 0.0f;
        float ycl0 = fminf(fmaxf(yc0, 0.0f), (float)(H - 1));
        float ycl1 = fminf(fmaxf(yc1, 0.0f), (float)(H - 1));
        int yl0 = min(max((int)floorf(ycl0), 0), H - 2);
        int yl1 = min(max((int)floorf(ycl1), 0), H - 2);
        float ly0 = ycl0 - (float)yl0, hy0 = 1.0f - ly0;
        float ly1 = ycl1 - (float)yl1, hy1 = 1.0f - ly1;
        float wy0 = 0.25f * vy0 * hy0, wy1 = 0.25f * vy0 * ly0;
        float wy2 = 0.25f * vy1 * hy1, wy3 = 0.25f * vy1 * ly1;
        int q = yl1 - yl0;
        float wr0 = wy0 + ((q == 0) ? wy2 : 0.0f);
        float wr1 = wy1 + ((q == 0) ? wy3 : wy2);
        float wr2 = (q == 0) ? 0.0f : wy3;
        int row0 = yl0;
        int row2 = min(yl0 + 2, H - 1);
        float wv[3][4];
        #pragma unroll
        for (int k = 0; k < 4; ++k) {
            wv[0][k] = wr0 * w4[k]; wv[1][k] = wr1 * w4[k]; wv[2][k] = wr2 * w4[k];
        }
        int c0 = superchunk * 64 + cbase;
        const int HW = H * W;
        unsigned slab = (unsigned)(b * C_TOTAL + c0) * (unsigned)HW;
        unsigned o0 = slab + (unsigned)(row0 * W + xb);
        unsigned o1 = o0 + (unsigned)W;
        unsigned o2 = slab + (unsigned)(row2 * W + xb);
        int ldsbase = cbase * NPOS + s;
        f4v a0 = *(const f4v*)(data + o0);
        f4v a1 = *(const f4v*)(data + o1);
        f4v a2 = *(const f4v*)(data + o2);
        int jj = 0;
        for (; jj < cnt - 1; ++jj) {
            o0 += HW; o1 += HW; o2 += HW;
            f4v b0 = *(const f4v*)(data + o0);
            f4v b1 = *(const f4v*)(data + o1);
            f4v b2 = *(const f4v*)(data + o2);
            float acc = wv[0][0]*a0.x + wv[0][1]*a0.y + wv[0][2]*a0.z + wv[0][3]*a0.w
                      + wv[1][0]*a1.x + wv[1][1]*a1.y + wv[1][2]*a1.z + wv[1][3]*a1.w
                      + wv[2][0]*a2.x + wv[2][1]*a2.y + wv[2][2]*a2.z + wv[2][3]*a2.w;
            so[ldsbase + jj * NPOS] = acc;
            a0 = b0; a1 = b1; a2 = b2;
        }
        float acc = wv[0][0]*a0.x + wv[0][1]*a0.y + wv[0][2]*a0.z + wv[0][3]*a0.w
                  + wv[1][0]*a1.x + wv[1][1]*a1.y + wv[1][2]*a1.z + wv[1][3]*a1.w
                  + wv[2][0]*a2.x + wv[2][1]*a2.y + wv[2][2]*a2.z + wv[2][3]*a2.w;
        so[ldsbase + jj * NPOS] = acc;
    }
    __syncthreads();
    unsigned base = (unsigned)(n * C_TOTAL + superchunk * 64) * NPOS;
    f4a* dst = (f4a*)(out + base);
    const f4a* src = (const f4a*)so;
    int tid = threadIdx.x;
    dst[tid] = src[tid];
    dst[256 + tid] = src[256 + tid];
    dst[512 + tid] = src[512 + tid];
    if (tid < 16) dst[768 + tid] = src[768 + tid];
}

extern "C" void kernel_launch(void* const* d_in, const int* in_sizes, int n_in,
                              void* d_out, int out_size, void* d_ws, size_t ws_size,
                              hipStream_t stream) {
    const float* data = (const float*)d_in[0];
    const float* rois = (const float*)d_in[1];
    float* out = (float*)d_out;
    const int N = in_sizes[1] / 5;

    if (ws_size >= TB_BYTES) {
        __hip_bfloat16* Tb = (__hip_bfloat16*)d_ws;
        transpose_bf16_kernel<<<2 * HH * NXCD, 256, 0, stream>>>(data, Tb);
        roi_mfma_kernel<<<N * NXCD, 256, 0, stream>>>(
            (const unsigned int*)d_ws, rois, out, N);
    } else {
        roi_align_fallback<<<N * 16, 256, 0, stream>>>(data, rois, out, HH, WW, N);
    }
}

// Round 14
// 43.067 us; speedup vs baseline: 1.6340x; 1.0828x over previous
//
#include <hip/hip_runtime.h>
#include <hip/hip_bf16.h>

#define SPATIAL_SCALE 0.0625f
#define PH 7
#define PW 7
#define C_TOTAL 1024
#define NXCD 8
#define NPOS 49
#define CG 128
#define HH 50
#define WW 50
#define TB_BYTES (2ULL * NXCD * HH * WW * CG * 2ULL)   // 10,240,000 B (bf16)

typedef short bf16x8 __attribute__((ext_vector_type(8)));
typedef float f32x16 __attribute__((ext_vector_type(16)));
typedef float f4a __attribute__((ext_vector_type(4), aligned(16)));
typedef float f4v __attribute__((ext_vector_type(4), aligned(8)));
typedef unsigned int u4v __attribute__((ext_vector_type(4), aligned(16)));
typedef unsigned int u2v __attribute__((ext_vector_type(2), aligned(8)));

// ---- Kernel 1: NCHW fp32 -> [b][g][y][x][c128] bf16 channels-last ----------
__global__ __launch_bounds__(256) void transpose_bf16_kernel(
    const float* __restrict__ in, __hip_bfloat16* __restrict__ Tb)
{
    __shared__ float lds[CG][WW + 1];
    int bid = blockIdx.x;            // (b*50 + y)*8 + g
    int g = bid & 7;
    int r = bid >> 3;
    int y = r % HH;
    int b = r / HH;
    int tid = threadIdx.x;

    const float* src = in + (size_t)(b * C_TOTAL + g * CG) * (HH * WW) + y * WW;
    #pragma unroll
    for (int it = 0; it < 25; ++it) {        // 6400 = 128c x 50x
        int idx = it * 256 + tid;
        int c = idx / WW;
        int x = idx - c * WW;
        lds[c][x] = src[c * (HH * WW) + x];
    }
    __syncthreads();
    __hip_bfloat16* dst = Tb + (size_t)((b * NXCD + g) * (HH * WW) + y * WW) * CG;
    #pragma unroll
    for (int it = 0; it < 25; ++it) {
        int idx = it * 256 + tid;
        int x = idx >> 7;                    // 0..49
        int c = idx & 127;
        dst[x * CG + c] = __float2bfloat16(lds[c][x]);
    }
}

// ---- Kernel 2: MFMA ROI align, A-operand in registers, 16.4KB LDS ----------
// Block = (roi n, slab g): 128 ch, 4 waves, 8 blocks/CU. blockIdx&7=g -> XCD.
// out[bin][ch] = sum_tap W[bin][tap]*V[tap][ch], taps = 16x16 window chunked
// 4 rows (K=64) at a time. A row = lane&31 = the lane's OWN bin -> W row held
// in 3 bf16x8 registers (rel 0..2), selected per K-slice by cndmask. V staged
// coalesced (R13-proven repack + rotation swizzle). C staged through Vl
// (reused as [64][52] f32) in two 64-channel passes -> coalesced writeback.
__global__ __launch_bounds__(256) void roi_mfma_kernel(
    const unsigned int* __restrict__ Tw,   // channels-last bf16 viewed as u32
    const float* __restrict__ rois,
    float* __restrict__ out, int N)
{
    __shared__ __align__(16) short Vl[CG * 64];      // 16384 B
    float* solh = (float*)Vl;                        // [64][52] f32 = 13312 B

    int g   = blockIdx.x & (NXCD - 1);
    int n   = blockIdx.x >> 3;
    int tid = threadIdx.x;
    int wid = tid >> 6, lane = tid & 63, lane31 = lane & 31, hi = lane >> 5;

    const float* roi = rois + n * 5;
    int   b  = (int)roi[0];
    float x1 = roi[1] * SPATIAL_SCALE;
    float y1 = roi[2] * SPATIAL_SCALE;
    float x2 = roi[3] * SPATIAL_SCALE;
    float y2 = roi[4] * SPATIAL_SCALE;
    float bin_w = fmaxf(x2 - x1, 1.0f) * (1.0f / 7.0f);
    float bin_h = fmaxf(y2 - y1, 1.0f) * (1.0f / 7.0f);
    float hbw = 0.5f * bin_w, hbh = 0.5f * bin_h;
    float xq = x1 + 0.5f * hbw;              // xc0(pw) = pw*bin_w + xq
    float yq = y1 + 0.5f * hbh;

    // ---- uniform window base (all threads, redundant; no LDS) ----
    int minr = 48, maxr0 = 0, minc = 48;
    #pragma unroll
    for (int i = 0; i < 7; ++i) {
        float yc = fmaf((float)i, bin_h, yq);
        int yl = min(max((int)floorf(fminf(fmaxf(yc, 0.0f), 49.0f)), 0), 48);
        minr = min(minr, yl); maxr0 = max(maxr0, yl);
        float xc = fmaf((float)i, bin_w, xq);
        int xl = min(max((int)floorf(fminf(fmaxf(xc, 0.0f), 49.0f)), 0), 48);
        minc = min(minc, xl);
    }
    int rb = min(minr, 34);
    int cb = min(minc, 34) & ~1;             // even -> 4B-aligned staging
    int nch = ((min(maxr0 + 2, 49) - rb) >> 2) + 1;   // 1..4 chunks

    // ---- own-bin params (A row = lane's bin; bins >48 get zero weights) ----
    int bin = (wid >> 1) * 32 + lane31;      // 0..63
    int ph = bin / 7;                        // up to 9 for dummy bins
    int pw = bin - ph * 7;
    float wr0, wr1, wr2; int yl0;
    {
        float c0 = fmaf((float)ph, bin_h, yq);
        float c1 = c0 + hbh;
        float v0 = (c0 >= -1.0f && c0 <= 50.0f) ? 1.0f : 0.0f;
        float v1 = (c1 >= -1.0f && c1 <= 50.0f) ? 1.0f : 0.0f;
        float cl0 = fminf(fmaxf(c0, 0.0f), 49.0f);
        float cl1 = fminf(fmaxf(c1, 0.0f), 49.0f);
        int l0 = min(max((int)floorf(cl0), 0), 48);
        int l1 = min(max((int)floorf(cl1), 0), 48);
        float f0 = cl0 - (float)l0, g0 = 1.0f - f0;
        float f1 = cl1 - (float)l1, g1 = 1.0f - f1;
        int dq = l1 - l0;                    // 0 or 1
        wr0 = v0 * g0 + ((dq == 0) ? v1 * g1 : 0.0f);
        wr1 = v0 * f0 + ((dq == 0) ? v1 * f1 : v1 * g1);
        wr2 = (dq == 0) ? 0.0f : v1 * f1;
        yl0 = l0;
    }
    float u0, u1, u2; int xl0;
    {
        float c0 = fmaf((float)pw, bin_w, xq);
        float c1 = c0 + hbw;
        float v0 = (c0 >= -1.0f && c0 <= 50.0f) ? 1.0f : 0.0f;
        float v1 = (c1 >= -1.0f && c1 <= 50.0f) ? 1.0f : 0.0f;
        float cl0 = fminf(fmaxf(c0, 0.0f), 49.0f);
        float cl1 = fminf(fmaxf(c1, 0.0f), 49.0f);
        int l0 = min(max((int)floorf(cl0), 0), 48);
        int l1 = min(max((int)floorf(cl1), 0), 48);
        float f0 = cl0 - (float)l0, g0 = 1.0f - f0;
        float f1 = cl1 - (float)l1, g1 = 1.0f - f1;
        int dq = l1 - l0;
        u0 = v0 * g0 + ((dq == 0) ? v1 * g1 : 0.0f);
        u1 = v0 * f0 + ((dq == 0) ? v1 * f1 : v1 * g1);
        u2 = (dq == 0) ? 0.0f : v1 * f1;
        xl0 = l0;
    }
    int ry0 = yl0 - rb;                      // 0..13
    int cc0 = xl0 - cb;                      // 0..13

    // ---- A rows in registers: cols hi*8+j of the 16-col window ----
    bf16x8 aw0, aw1, aw2;
    #pragma unroll
    for (int j = 0; j < 8; ++j) {
        int colj = hi * 8 + j;
        float uc = (colj == cc0) ? u0
                 : ((colj == cc0 + 1) ? u1 : ((colj == cc0 + 2) ? u2 : 0.0f));
        __hip_bfloat16 h0 = __float2bfloat16(wr0 * uc);
        __hip_bfloat16 h1 = __float2bfloat16(wr1 * uc);
        __hip_bfloat16 h2 = __float2bfloat16(wr2 * uc);
        aw0[j] = *(short*)&h0;
        aw1[j] = *(short*)&h1;
        aw2[j] = *(short*)&h2;
    }
    bf16x8 awz = {};

    // ---- MFMA main loop ----
    int ch0 = (wid & 1) * 32 + lane31;       // Ntile pair {ch0, ch0+64}
    int ch1 = ch0 + 64;
    int rot0 = ch0 >> 2, rot1 = ch1 >> 2;
    int cq   = tid & 31;                     // staging: u32-pair -> 4 channels
    int half = (tid >> 5) & 1;               // taps 0-7 / 8-15 within row
    int tg   = tid >> 6;                     // row 0..3 of chunk
    const unsigned int* slabU = Tw + (size_t)(b * NXCD + g) * (HH * WW * 64);

    f32x16 acc0 = {}, acc1 = {};
    for (int chunk = 0; chunk < nch; ++chunk) {
        int r0 = rb + chunk * 4 + tg;        // <= 49 always (rb<=34)
        const unsigned int* rp = slabU + (r0 * WW + cb + half * 8) * 64 + 2 * cq;
        u2v A0 = *(const u2v*)(rp);
        u2v A1 = *(const u2v*)(rp + 64);
        u2v A2 = *(const u2v*)(rp + 128);
        u2v A3 = *(const u2v*)(rp + 192);
        u2v A4 = *(const u2v*)(rp + 256);
        u2v A5 = *(const u2v*)(rp + 320);
        u2v A6 = *(const u2v*)(rp + 384);
        u2v A7 = *(const u2v*)(rp + 448);
        u4v lo0, hi0, lo1, hi1;
        lo0[0] = (A0[0] & 0xffffu) | (A1[0] << 16);
        lo0[1] = (A2[0] & 0xffffu) | (A3[0] << 16);
        lo0[2] = (A4[0] & 0xffffu) | (A5[0] << 16);
        lo0[3] = (A6[0] & 0xffffu) | (A7[0] << 16);
        hi0[0] = (A0[0] >> 16) | (A1[0] & 0xffff0000u);
        hi0[1] = (A2[0] >> 16) | (A3[0] & 0xffff0000u);
        hi0[2] = (A4[0] >> 16) | (A5[0] & 0xffff0000u);
        hi0[3] = (A6[0] >> 16) | (A7[0] & 0xffff0000u);
        lo1[0] = (A0[1] & 0xffffu) | (A1[1] << 16);
        lo1[1] = (A2[1] & 0xffffu) | (A3[1] << 16);
        lo1[2] = (A4[1] & 0xffffu) | (A5[1] << 16);
        lo1[3] = (A6[1] & 0xffffu) | (A7[1] << 16);
        hi1[0] = (A0[1] >> 16) | (A1[1] & 0xffff0000u);
        hi1[1] = (A2[1] >> 16) | (A3[1] & 0xffff0000u);
        hi1[2] = (A4[1] >> 16) | (A5[1] & 0xffff0000u);
        hi1[3] = (A6[1] >> 16) | (A7[1] & 0xffff0000u);
        int seg = tg * 2 + half;
        int chA = 4 * cq;
        int rotw = (seg + cq) & 7;           // rotate by ch>>2 (= cq)
        *(u4v*)&Vl[(chA    ) * 64 + rotw * 8] = lo0;
        *(u4v*)&Vl[(chA + 1) * 64 + rotw * 8] = hi0;
        *(u4v*)&Vl[(chA + 2) * 64 + rotw * 8] = lo1;
        *(u4v*)&Vl[(chA + 3) * 64 + rotw * 8] = hi1;
        __syncthreads();
        #pragma unroll
        for (int kl = 0; kl < 4; ++kl) {
            int rel = chunk * 4 + kl - ry0;
            bf16x8 av = (rel == 0) ? aw0
                      : ((rel == 1) ? aw1 : ((rel == 2) ? aw2 : awz));
            bf16x8 bv0 = *(const bf16x8*)&Vl[ch0 * 64 + (((kl * 2 + hi) + rot0) & 7) * 8];
            bf16x8 bv1 = *(const bf16x8*)&Vl[ch1 * 64 + (((kl * 2 + hi) + rot1) & 7) * 8];
            acc0 = __builtin_amdgcn_mfma_f32_32x32x16_bf16(av, bv0, acc0, 0, 0, 0);
            acc1 = __builtin_amdgcn_mfma_f32_32x32x16_bf16(av, bv1, acc1, 0, 0, 0);
        }
        __syncthreads();
    }

    // ---- epilogue: two 64-channel passes through Vl-as-solh ----
    int m = wid >> 1;
    int obase = (n * C_TOTAL + g * CG) * NPOS;

    #pragma unroll
    for (int q = 0; q < 4; ++q) {            // pass 0: acc0, ch 0..63
        int bin0 = m * 32 + 8 * q + 4 * hi;  // C/D row = (reg&3)+8*(reg>>2)+4*hi
        if (bin0 <= 48) {
            f4a v;
            v[0] = acc0[4*q]; v[1] = acc0[4*q+1]; v[2] = acc0[4*q+2]; v[3] = acc0[4*q+3];
            *(f4a*)&solh[ch0 * 52 + bin0] = v;
        }
    }
    __syncthreads();
    #pragma unroll
    for (int k2 = 0; k2 < 4; ++k2) {
        int t = k2 * 256 + tid;
        if (t < 784) {                       // 64*49/4
            f4a o;
            #pragma unroll
            for (int i2 = 0; i2 < 4; ++i2) {
                int f = 4 * t + i2;
                int fch = f / 49;
                int fbin = f - fch * 49;
                o[i2] = solh[fch * 52 + fbin] * 0.25f;
            }
            *(f4a*)(out + obase + 4 * t) = o;
        }
    }
    __syncthreads();
    #pragma unroll
    for (int q = 0; q < 4; ++q) {            // pass 1: acc1, ch 64..127
        int bin0 = m * 32 + 8 * q + 4 * hi;
        if (bin0 <= 48) {
            f4a v;
            v[0] = acc1[4*q]; v[1] = acc1[4*q+1]; v[2] = acc1[4*q+2]; v[3] = acc1[4*q+3];
            *(f4a*)&solh[ch0 * 52 + bin0] = v;   // local ch = ch1-64 = ch0
        }
    }
    __syncthreads();
    #pragma unroll
    for (int k2 = 0; k2 < 4; ++k2) {
        int t = k2 * 256 + tid;
        if (t < 784) {
            f4a o;
            #pragma unroll
            for (int i2 = 0; i2 < 4; ++i2) {
                int f = 4 * t + i2;
                int fch = f / 49;
                int fbin = f - fch * 49;
                o[i2] = solh[fch * 52 + fbin] * 0.25f;
            }
            *(f4a*)(out + obase + 64 * NPOS + 4 * t) = o;
        }
    }
}

// ---- Fallback (fp32 direct, ~R7) if workspace too small --------------------
__global__ __launch_bounds__(256) void roi_align_fallback(
    const float* __restrict__ data, const float* __restrict__ rois,
    float* __restrict__ out, int H, int W, int N)
{
    __shared__ __align__(16) float so[64 * NPOS];
    int i   = blockIdx.x;
    int xcd = i & (NXCD - 1);
    int j   = i >> 3;
    int scl = (j >= N) ? 1 : 0;
    int n   = j - scl * N;
    int superchunk = xcd * 2 + scl;
    int t = threadIdx.x;
    bool active = (t < 5 * NPOS);
    int tt = active ? t : 0;
    int s  = tt % NPOS;
    int g  = tt / NPOS;
    int cbase = g * 13;
    int cnt = (g < 4) ? 13 : 12;
    int pw = s % PW;
    int ph = s / PW;
    if (active) {
        const float* roi = rois + n * 5;
        int   b  = (int)roi[0];
        float x1 = roi[1] * SPATIAL_SCALE, y1 = roi[2] * SPATIAL_SCALE;
        float x2 = roi[3] * SPATIAL_SCALE, y2 = roi[4] * SPATIAL_SCALE;
        float roi_w = fmaxf(x2 - x1, 1.0f), roi_h = fmaxf(y2 - y1, 1.0f);
        float bin_w = roi_w * (1.0f / PW), bin_h = roi_h * (1.0f / PH);
        float xc0 = x1 + ((float)(pw * 2 + 0) + 0.5f) * bin_w * 0.5f;
        float xc1 = x1 + ((float)(pw * 2 + 1) + 0.5f) * bin_w * 0.5f;
        float vx0 = (xc0 >= -1.0f && xc0 <= (float)W) ? 1.0f : 0.0f;
        float vx1 = (xc1 >= -1.0f && xc1 <= (float)W) ? 1.0f : 0.0f;
        float xcl0 = fminf(fmaxf(xc0, 0.0f), (float)(W - 1));
        float xcl1 = fminf(fmaxf(xc1, 0.0f), (float)(W - 1));
        int xl0 = min(max((int)floorf(xcl0), 0), W - 2);
        int xl1 = min(max((int)floorf(xcl1), 0), W - 2);
        float lx0 = xcl0 - (float)xl0, hx0 = 1.0f - lx0;
        float lx1 = xcl1 - (float)xl1, hx1 = 1.0f - lx1;
        int xb = min(xl0 & ~1, W - 4);
        int p0 = xl0 - xb, p1 = xl1 - xb;
        float w4[4];
        #pragma unroll
        for (int k = 0; k < 4; ++k) {
            float a = (p0 == k) ? hx0 : ((p0 + 1 == k) ? lx0 : 0.0f);
            float c = (p1 == k) ? hx1 : ((p1 + 1 == k) ? lx1 : 0.0f);
            w4[k] = vx0 * a + vx1 * c;
        }
        float yc0 = y1 + ((float)(ph * 2 + 0) + 0.5f) * bin_h * 0.5f;
        float yc1 = y1 + ((float)(ph * 2 + 1) + 0.5f) * bin_h * 0.5f;
        float vy0 = (yc0 >= -1.0f && yc0 <= (float)H) ? 1.0f : 0.0f;
        float vy1 = (yc1 >= -1.0f && yc1 <= (float)H) ? 1.0f : 0.0f;
        float ycl0 = fminf(fmaxf(yc0, 0.0f), (float)(H - 1));
        float ycl1 = fminf(fmaxf(yc1, 0.0f), (float)(H - 1));
        int yl0 = min(max((int)floorf(ycl0), 0), H - 2);
        int yl1 = min(max((int)floorf(ycl1), 0), H - 2);
        float ly0 = ycl0 - (float)yl0, hy0 = 1.0f - ly0;
        float ly1 = ycl1 - (float)yl1, hy1 = 1.0f - ly1;
        float wy0 = 0.25f * vy0 * hy0, wy1 = 0.25f * vy0 * ly0;
        float wy2 = 0.25f * vy1 * hy1, wy3 = 0.25f * vy1 * ly1;
        int q = yl1 - yl0;
        float wr0 = wy0 + ((q == 0) ? wy2 : 0.0f);
        float wr1 = wy1 + ((q == 0) ? wy3 : wy2);
        float wr2 = (q == 0) ? 0.0f : wy3;
        int row0 = yl0;
        int row2 = min(yl0 + 2, H - 1);
        float wv[3][4];
        #pragma unroll
        for (int k = 0; k < 4; ++k) {
            wv[0][k] = wr0 * w4[k]; wv[1][k] = wr1 * w4[k]; wv[2][k] = wr2 * w4[k];
        }
        int c0 = superchunk * 64 + cbase;
        const int HW = H * W;
        unsigned slab = (unsigned)(b * C_TOTAL + c0) * (unsigned)HW;
        unsigned o0 = slab + (unsigned)(row0 * W + xb);
        unsigned o1 = o0 + (unsigned)W;
        unsigned o2 = slab + (unsigned)(row2 * W + xb);
        int ldsbase = cbase * NPOS + s;
        f4v a0 = *(const f4v*)(data + o0);
        f4v a1 = *(const f4v*)(data + o1);
        f4v a2 = *(const f4v*)(data + o2);
        int jj = 0;
        for (; jj < cnt - 1; ++jj) {
            o0 += HW; o1 += HW; o2 += HW;
            f4v b0 = *(const f4v*)(data + o0);
            f4v b1 = *(const f4v*)(data + o1);
            f4v b2 = *(const f4v*)(data + o2);
            float acc = wv[0][0]*a0.x + wv[0][1]*a0.y + wv[0][2]*a0.z + wv[0][3]*a0.w
                      + wv[1][0]*a1.x + wv[1][1]*a1.y + wv[1][2]*a1.z + wv[1][3]*a1.w
                      + wv[2][0]*a2.x + wv[2][1]*a2.y + wv[2][2]*a2.z + wv[2][3]*a2.w;
            so[ldsbase + jj * NPOS] = acc;
            a0 = b0; a1 = b1; a2 = b2;
        }
        float acc = wv[0][0]*a0.x + wv[0][1]*a0.y + wv[0][2]*a0.z + wv[0][3]*a0.w
                  + wv[1][0]*a1.x + wv[1][1]*a1.y + wv[1][2]*a1.z + wv[1][3]*a1.w
                  + wv[2][0]*a2.x + wv[2][1]*a2.y + wv[2][2]*a2.z + wv[2][3]*a2.w;
        so[ldsbase + jj * NPOS] = acc;
    }
    __syncthreads();
    unsigned base = (unsigned)(n * C_TOTAL + superchunk * 64) * NPOS;
    f4a* dst = (f4a*)(out + base);
    const f4a* src = (const f4a*)so;
    int tid = threadIdx.x;
    dst[tid] = src[tid];
    dst[256 + tid] = src[256 + tid];
    dst[512 + tid] = src[512 + tid];
    if (tid < 16) dst[768 + tid] = src[768 + tid];
}

extern "C" void kernel_launch(void* const* d_in, const int* in_sizes, int n_in,
                              void* d_out, int out_size, void* d_ws, size_t ws_size,
                              hipStream_t stream) {
    const float* data = (const float*)d_in[0];
    const float* rois = (const float*)d_in[1];
    float* out = (float*)d_out;
    const int N = in_sizes[1] / 5;

    if (ws_size >= TB_BYTES) {
        __hip_bfloat16* Tb = (__hip_bfloat16*)d_ws;
        transpose_bf16_kernel<<<2 * HH * NXCD, 256, 0, stream>>>(data, Tb);
        roi_mfma_kernel<<<N * NXCD, 256, 0, stream>>>(
            (const unsigned int*)d_ws, rois, out, N);
    } else {
        roi_align_fallback<<<N * 16, 256, 0, stream>>>(data, rois, out, HH, WW, N);
    }
}